// Round 1
// baseline (2226.040 us; speedup 1.0000x reference)
//
#include <hip/hip_runtime.h>
#include <hip/hip_bf16.h>
#include <math.h>

// Problem constants
#define Bn   2
#define Sn   1800
#define Dn   128
#define Hn   8
#define DKn  16
#define DFFn 512
#define Ln   6
#define Vn   16
#define LATn 1024
#define BSn  3600        // B*S
#define SDn  230400      // S*D

// ---------------------------------------------------------------------------
// h = relu(latent @ lp_w1 + lp_b1)   [2, 256]
// ---------------------------------------------------------------------------
__global__ __launch_bounds__(256) void lat_h_kernel(
    const float* __restrict__ latent, const float* __restrict__ w1,
    const float* __restrict__ b1, float* __restrict__ h)
{
    __shared__ float ls[LATn];
    const int b = blockIdx.x;
    const int t = threadIdx.x;
    for (int k = t; k < LATn; k += 256) ls[k] = latent[b * LATn + k];
    __syncthreads();
    float acc = 0.f;
    #pragma unroll 8
    for (int k = 0; k < LATn; ++k) acc = fmaf(ls[k], w1[(size_t)k * 256 + t], acc);
    h[b * 256 + t] = fmaxf(acc + b1[t], 0.f);
}

// ---------------------------------------------------------------------------
// dec = h @ lp_w2 + lp_b2 + pos_encoding ; also copies to enc
// grid 900 x 256 threads, one output column j in [0, 230400) per thread
// ---------------------------------------------------------------------------
__global__ __launch_bounds__(256) void dec_kernel(
    const float* __restrict__ h, const float* __restrict__ w2,
    const float* __restrict__ b2, float* __restrict__ x, float* __restrict__ enc)
{
    __shared__ float hs[512];
    const int t = threadIdx.x;
    hs[t] = h[t];
    hs[256 + t] = h[256 + t];
    __syncthreads();
    const int j = blockIdx.x * 256 + t;
    float a0 = 0.f, a1 = 0.f;
    #pragma unroll 8
    for (int k = 0; k < 256; ++k) {
        float w = w2[(size_t)k * SDn + j];
        a0 = fmaf(hs[k], w, a0);
        a1 = fmaf(hs[256 + k], w, a1);
    }
    const int s = j >> 7, d = j & 127;
    const int i2 = d >> 1;
    // div = exp(-(2*i2) * ln(10000)/128)
    const float freq = __expf(-(float)(2 * i2) * (9.210340371976184f / 128.f));
    const float ang = (float)s * freq;
    const float pe = (d & 1) ? cosf(ang) : sinf(ang);
    const float bias = b2[j] + pe;
    const float v0 = a0 + bias;
    const float v1 = a1 + bias;
    x[j] = v0;          enc[j] = v0;
    x[SDn + j] = v1;    enc[SDn + j] = v1;
}

// ---------------------------------------------------------------------------
// Generic tiled matmul C = A @ W + bias  (optional relu)
// 64x64 tile, BK=16, 256 threads, 4x4 per thread. N must be multiple of 64.
// blockIdx.z in {0,1,2} selects (A,W,bias,C) triple -> fused QKV in one launch
// ---------------------------------------------------------------------------
__global__ __launch_bounds__(256) void mm64_kernel(
    const float* __restrict__ A0, const float* __restrict__ A1, const float* __restrict__ A2,
    const float* __restrict__ W0, const float* __restrict__ W1, const float* __restrict__ W2,
    const float* __restrict__ B0, const float* __restrict__ B1, const float* __restrict__ B2,
    float* __restrict__ C0, float* __restrict__ C1, float* __restrict__ C2,
    int M, int N, int K, int relu)
{
    const int z = blockIdx.z;
    const float* A = (z == 0) ? A0 : (z == 1) ? A1 : A2;
    const float* W = (z == 0) ? W0 : (z == 1) ? W1 : W2;
    const float* Bi = (z == 0) ? B0 : (z == 1) ? B1 : B2;
    float* C = (z == 0) ? C0 : (z == 1) ? C1 : C2;

    __shared__ float As[16][64];   // [k][m]
    __shared__ float Wsh[16][64];  // [k][n]

    const int t = threadIdx.x;
    const int tx = t & 15, ty = t >> 4;
    const int m0 = blockIdx.x * 64;
    const int n0 = blockIdx.y * 64;

    const int arow = t >> 2;          // 0..63
    const int acol = (t & 3) << 2;    // 0,4,8,12
    const int wrow = t >> 4;          // 0..15
    const int wcol = (t & 15) << 2;   // 0..60

    float acc[4][4] = {};

    for (int k0 = 0; k0 < K; k0 += 16) {
        float4 av = make_float4(0.f, 0.f, 0.f, 0.f);
        if (m0 + arow < M)
            av = *(const float4*)&A[(size_t)(m0 + arow) * K + k0 + acol];
        As[acol + 0][arow] = av.x;
        As[acol + 1][arow] = av.y;
        As[acol + 2][arow] = av.z;
        As[acol + 3][arow] = av.w;
        float4 wv = *(const float4*)&W[(size_t)(k0 + wrow) * N + n0 + wcol];
        *(float4*)&Wsh[wrow][wcol] = wv;
        __syncthreads();
        #pragma unroll
        for (int kk = 0; kk < 16; ++kk) {
            float a4[4], b4[4];
            #pragma unroll
            for (int ii = 0; ii < 4; ++ii) a4[ii] = As[kk][ty * 4 + ii];
            #pragma unroll
            for (int jj = 0; jj < 4; ++jj) b4[jj] = Wsh[kk][tx * 4 + jj];
            #pragma unroll
            for (int ii = 0; ii < 4; ++ii)
                #pragma unroll
                for (int jj = 0; jj < 4; ++jj)
                    acc[ii][jj] = fmaf(a4[ii], b4[jj], acc[ii][jj]);
        }
        __syncthreads();
    }

    #pragma unroll
    for (int ii = 0; ii < 4; ++ii) {
        const int r = m0 + ty * 4 + ii;
        if (r >= M) continue;
        #pragma unroll
        for (int jj = 0; jj < 4; ++jj) {
            const int c = n0 + tx * 4 + jj;
            float vv = acc[ii][jj] + Bi[c];
            if (relu) vv = fmaxf(vv, 0.f);
            C[(size_t)r * N + c] = vv;
        }
    }
}

// ---------------------------------------------------------------------------
// Flash attention. grid (29 qtiles, 16 b*h), 256 threads = 4 waves.
// Each wave owns 64 query rows (one per lane) and processes KV tiles
// wave, wave+4, ... with private online-softmax state; LDS merge at end.
// SMASK=true -> strictly-upper-triangle mask (keep j > i), value -1e9
// (reference bug reproduced; fully-masked last row -> uniform avg of V).
// ---------------------------------------------------------------------------
template <bool SMASK>
__global__ __launch_bounds__(256) void flash_kernel(
    const float* __restrict__ Q, const float* __restrict__ Kg,
    const float* __restrict__ Vg, float* __restrict__ O)
{
    const int qt = blockIdx.x;
    const int bh = blockIdx.y;
    const int b = bh >> 3, h = bh & 7;
    const int wave = threadIdx.x >> 6;
    const int lane = threadIdx.x & 63;

    __shared__ float sKV[4][2048];  // per wave: K[64][16] @0, V[64][16] @1024
    float* Ks = &sKV[wave][0];
    float* Vs = &sKV[wave][1024];

    const int i = qt * 64 + lane;       // query row in [0, 1800)
    const int iq = (i < Sn) ? i : (Sn - 1);
    const float* qp = &Q[((size_t)b * Sn + iq) * Dn + h * DKn];
    float q[16];
    #pragma unroll
    for (int d = 0; d < 16; d += 4) {
        float4 v4 = *(const float4*)&qp[d];
        q[d] = v4.x; q[d + 1] = v4.y; q[d + 2] = v4.z; q[d + 3] = v4.w;
    }

    float m = -INFINITY, l = 0.f;
    float acc[16] = {};

    const int NT = (Sn + 63) / 64;  // 29
    const int r16 = lane >> 2;           // 0..15
    const int c4 = (lane & 3) << 2;      // 0,4,8,12

    for (int tk = wave; tk < NT; tk += 4) {
        // stage K,V tile into this wave's LDS region
        #pragma unroll
        for (int rr = 0; rr < 4; ++rr) {
            const int row = r16 + rr * 16;
            int grow = tk * 64 + row;
            if (grow >= Sn) grow = Sn - 1;  // clamped; masked below via -1e30
            const size_t gb = ((size_t)b * Sn + grow) * Dn + h * DKn + c4;
            float4 kv = *(const float4*)&Kg[gb];
            float4 vv = *(const float4*)&Vg[gb];
            *(float4*)&Ks[row * 16 + c4] = kv;
            *(float4*)&Vs[row * 16 + c4] = vv;
        }
        // same-wave LDS producer->consumer: drain DS queue, block reordering
        asm volatile("s_waitcnt lgkmcnt(0)" ::: "memory");

        #pragma unroll
        for (int jc = 0; jc < 64; jc += 32) {
            float s[32];
            float mt = -INFINITY;
            #pragma unroll
            for (int jj = 0; jj < 32; ++jj) {
                const int j = jc + jj;
                float d0 = 0.f;
                #pragma unroll
                for (int d = 0; d < 16; ++d) d0 = fmaf(q[d], Ks[j * 16 + d], d0);
                const int jg = tk * 64 + j;
                float sv = d0 * 0.25f;  // 1/sqrt(16)
                if (SMASK) sv = (jg > i) ? sv : -1e9f;
                if (jg >= Sn) sv = -1e30f;
                s[jj] = sv;
                mt = fmaxf(mt, sv);
            }
            const float mnew = fmaxf(m, mt);
            const float corr = __expf(m - mnew);
            l *= corr;
            #pragma unroll
            for (int d = 0; d < 16; ++d) acc[d] *= corr;
            #pragma unroll
            for (int jj = 0; jj < 32; ++jj) {
                const float p = __expf(s[jj] - mnew);
                l += p;
                const int j = jc + jj;
                #pragma unroll
                for (int d = 0; d < 16; ++d) acc[d] = fmaf(p, Vs[j * 16 + d], acc[d]);
            }
            m = mnew;
        }
    }

    // merge the 4 per-wave partials (reuse sKV: 256*18 = 4608 floats < 8192)
    __syncthreads();
    float* mg = &sKV[0][0];
    float* my = mg + (wave * 64 + lane) * 18;
    my[0] = m;
    my[1] = l;
    #pragma unroll
    for (int d = 0; d < 16; ++d) my[2 + d] = acc[d];
    __syncthreads();
    if (wave == 0 && i < Sn) {
        float mstar = -INFINITY;
        #pragma unroll
        for (int w = 0; w < 4; ++w)
            mstar = fmaxf(mstar, mg[(w * 64 + lane) * 18]);
        float lsum = 0.f;
        float accf[16] = {};
        #pragma unroll
        for (int w = 0; w < 4; ++w) {
            const float* mw = mg + (w * 64 + lane) * 18;
            const float sc = __expf(mw[0] - mstar);
            lsum += mw[1] * sc;
            #pragma unroll
            for (int d = 0; d < 16; ++d) accf[d] = fmaf(mw[2 + d], sc, accf[d]);
        }
        const float inv = 1.f / lsum;
        float* op = &O[((size_t)b * Sn + i) * Dn + h * DKn];
        #pragma unroll
        for (int d = 0; d < 16; ++d) op[d] = accf[d] * inv;
    }
}

// ---------------------------------------------------------------------------
// y = LayerNorm(x + a) * g + b   (in-place on x). One wave per row, D=128.
// ---------------------------------------------------------------------------
__global__ __launch_bounds__(64) void ln_kernel(
    const float* __restrict__ X, const float* __restrict__ A,
    const float* __restrict__ g, const float* __restrict__ bb,
    float* __restrict__ Y)
{
    const int row = blockIdx.x;
    const int d = threadIdx.x;
    const size_t base = (size_t)row * 128;
    float v0 = X[base + d] + A[base + d];
    float v1 = X[base + d + 64] + A[base + d + 64];
    float sum = v0 + v1;
    #pragma unroll
    for (int off = 32; off > 0; off >>= 1) sum += __shfl_xor(sum, off);
    const float mu = sum * (1.f / 128.f);
    const float d0 = v0 - mu, d1 = v1 - mu;
    float vs = d0 * d0 + d1 * d1;
    #pragma unroll
    for (int off = 32; off > 0; off >>= 1) vs += __shfl_xor(vs, off);
    const float inv = rsqrtf(vs * (1.f / 128.f) + 1e-5f);
    Y[base + d] = d0 * inv * g[d] + bb[d];
    Y[base + d + 64] = d1 * inv * g[d + 64] + bb[d + 64];
}

// ---------------------------------------------------------------------------
// logits = x @ out_w + out_b   [3600,128]@[128,16]
// ---------------------------------------------------------------------------
__global__ __launch_bounds__(256) void out_kernel(
    const float* __restrict__ X, const float* __restrict__ W,
    const float* __restrict__ bb, float* __restrict__ out)
{
    const int t = threadIdx.x;
    const int n = t & 15;
    const int r = blockIdx.x * 16 + (t >> 4);
    if (r >= BSn) return;
    float acc = 0.f;
    #pragma unroll 8
    for (int k = 0; k < 128; ++k)
        acc = fmaf(X[(size_t)r * 128 + k], W[k * 16 + n], acc);
    out[(size_t)r * 16 + n] = acc + bb[n];
}

// ---------------------------------------------------------------------------
extern "C" void kernel_launch(void* const* d_in, const int* in_sizes, int n_in,
                              void* d_out, int out_size, void* d_ws, size_t ws_size,
                              hipStream_t stream)
{
    const float* latent = (const float*)d_in[0];
    const float* lp_w1  = (const float*)d_in[1];
    const float* lp_b1  = (const float*)d_in[2];
    const float* lp_w2  = (const float*)d_in[3];
    const float* lp_b2  = (const float*)d_in[4];
    const float* out_w  = (const float*)d_in[5];
    const float* out_b  = (const float*)d_in[6];
    const float* sa_wq = (const float*)d_in[7];  const float* sa_bq = (const float*)d_in[8];
    const float* sa_wk = (const float*)d_in[9];  const float* sa_bk = (const float*)d_in[10];
    const float* sa_wv = (const float*)d_in[11]; const float* sa_bv = (const float*)d_in[12];
    const float* sa_wo = (const float*)d_in[13]; const float* sa_bo = (const float*)d_in[14];
    const float* ca_wq = (const float*)d_in[15]; const float* ca_bq = (const float*)d_in[16];
    const float* ca_wk = (const float*)d_in[17]; const float* ca_bk = (const float*)d_in[18];
    const float* ca_wv = (const float*)d_in[19]; const float* ca_bv = (const float*)d_in[20];
    const float* ca_wo = (const float*)d_in[21]; const float* ca_bo = (const float*)d_in[22];
    const float* ff_w1 = (const float*)d_in[23]; const float* ff_b1 = (const float*)d_in[24];
    const float* ff_w2 = (const float*)d_in[25]; const float* ff_b2 = (const float*)d_in[26];
    const float* ln1g = (const float*)d_in[27]; const float* ln1b = (const float*)d_in[28];
    const float* ln2g = (const float*)d_in[29]; const float* ln2b = (const float*)d_in[30];
    const float* ln3g = (const float*)d_in[31]; const float* ln3b = (const float*)d_in[32];

    float* ws = (float*)d_ws;
    float* x    = ws + 0 * 460800;
    float* enc  = ws + 1 * 460800;
    float* qb   = ws + 2 * 460800;
    float* kb   = ws + 3 * 460800;
    float* vb   = ws + 4 * 460800;
    float* t0   = ws + 5 * 460800;
    float* t1   = ws + 6 * 460800;
    float* hff  = ws + 7 * 460800;             // 3600*512
    float* hlat = ws + 7 * 460800 + 1843200;   // 512

    lat_h_kernel<<<dim3(2), dim3(256), 0, stream>>>(latent, lp_w1, lp_b1, hlat);
    dec_kernel<<<dim3(900), dim3(256), 0, stream>>>(hlat, lp_w2, lp_b2, x, enc);

    const dim3 thr(256);
    const dim3 gProj(57, 2, 1), gQKV(57, 2, 3), gFF1(57, 8, 1);

    for (int i = 0; i < Ln; ++i) {
        const size_t wOff = (size_t)i * 128 * 128;
        const size_t bOff = (size_t)i * 128;
        const size_t fOff = (size_t)i * 128 * 512;
        const size_t f1b  = (size_t)i * 512;

        // ---- self attention ----
        mm64_kernel<<<gQKV, thr, 0, stream>>>(
            x, x, x,
            sa_wq + wOff, sa_wk + wOff, sa_wv + wOff,
            sa_bq + bOff, sa_bk + bOff, sa_bv + bOff,
            qb, kb, vb, BSn, 128, 128, 0);
        flash_kernel<true><<<dim3(29, 16), thr, 0, stream>>>(qb, kb, vb, t0);
        mm64_kernel<<<gProj, thr, 0, stream>>>(
            t0, t0, t0, sa_wo + wOff, sa_wo + wOff, sa_wo + wOff,
            sa_bo + bOff, sa_bo + bOff, sa_bo + bOff,
            t1, t1, t1, BSn, 128, 128, 0);
        ln_kernel<<<dim3(BSn), dim3(64), 0, stream>>>(x, t1, ln1g + bOff, ln1b + bOff, x);

        // ---- cross attention (K/V from enc) ----
        mm64_kernel<<<gQKV, thr, 0, stream>>>(
            x, enc, enc,
            ca_wq + wOff, ca_wk + wOff, ca_wv + wOff,
            ca_bq + bOff, ca_bk + bOff, ca_bv + bOff,
            qb, kb, vb, BSn, 128, 128, 0);
        flash_kernel<false><<<dim3(29, 16), thr, 0, stream>>>(qb, kb, vb, t0);
        mm64_kernel<<<gProj, thr, 0, stream>>>(
            t0, t0, t0, ca_wo + wOff, ca_wo + wOff, ca_wo + wOff,
            ca_bo + bOff, ca_bo + bOff, ca_bo + bOff,
            t1, t1, t1, BSn, 128, 128, 0);
        ln_kernel<<<dim3(BSn), dim3(64), 0, stream>>>(x, t1, ln2g + bOff, ln2b + bOff, x);

        // ---- ffn ----
        mm64_kernel<<<gFF1, thr, 0, stream>>>(
            x, x, x, ff_w1 + fOff, ff_w1 + fOff, ff_w1 + fOff,
            ff_b1 + f1b, ff_b1 + f1b, ff_b1 + f1b,
            hff, hff, hff, BSn, DFFn, 128, 1);
        mm64_kernel<<<gProj, thr, 0, stream>>>(
            hff, hff, hff, ff_w2 + fOff, ff_w2 + fOff, ff_w2 + fOff,
            ff_b2 + bOff, ff_b2 + bOff, ff_b2 + bOff,
            t1, t1, t1, BSn, 128, DFFn, 0);
        ln_kernel<<<dim3(BSn), dim3(64), 0, stream>>>(x, t1, ln3g + bOff, ln3b + bOff, x);
    }

    out_kernel<<<dim3(225), dim3(256), 0, stream>>>(x, out_w, out_b, (float*)d_out);
}

// Round 2
// 1380.426 us; speedup vs baseline: 1.6126x; 1.6126x over previous
//
#include <hip/hip_runtime.h>
#include <hip/hip_bf16.h>
#include <math.h>

// Problem constants
#define Bn   2
#define Sn   1800
#define Dn   128
#define Hn   8
#define DKn  16
#define DFFn 512
#define Ln   6
#define Vn   16
#define LATn 1024
#define BSn  3600        // B*S
#define SDn  230400      // S*D
#define NQT  57          // ceil(1800/32)
#define VTJ  1824        // padded j-dim of transposed V

typedef __attribute__((ext_vector_type(8))) short short8;   // 8 bf16 = 4 VGPR
typedef __attribute__((ext_vector_type(16))) float f32x16;
typedef unsigned int u32;

__device__ inline u32 cvtpk_bf16(float a, float b) {
    u32 r;
    asm("v_cvt_pk_bf16_f32 %0, %1, %2" : "=v"(r) : "v"(a), "v"(b));
    return r;
}

__device__ inline unsigned short f2bf(float f) {
    union { float f; u32 u; } x; x.f = f;
    u32 r = (x.u + 0x7FFFu + ((x.u >> 16) & 1u)) >> 16;
    return (unsigned short)r;
}

// ---------------------------------------------------------------------------
// h = relu(latent @ lp_w1 + lp_b1)   [2, 256]
// ---------------------------------------------------------------------------
__global__ __launch_bounds__(256) void lat_h_kernel(
    const float* __restrict__ latent, const float* __restrict__ w1,
    const float* __restrict__ b1, float* __restrict__ h)
{
    __shared__ float ls[LATn];
    const int b = blockIdx.x;
    const int t = threadIdx.x;
    for (int k = t; k < LATn; k += 256) ls[k] = latent[b * LATn + k];
    __syncthreads();
    float acc = 0.f;
    #pragma unroll 8
    for (int k = 0; k < LATn; ++k) acc = fmaf(ls[k], w1[(size_t)k * 256 + t], acc);
    h[b * 256 + t] = fmaxf(acc + b1[t], 0.f);
}

// ---------------------------------------------------------------------------
// dec = h @ lp_w2 + lp_b2 + pos_encoding ; also copies to enc
// ---------------------------------------------------------------------------
__global__ __launch_bounds__(256) void dec_kernel(
    const float* __restrict__ h, const float* __restrict__ w2,
    const float* __restrict__ b2, float* __restrict__ x, float* __restrict__ enc)
{
    __shared__ float hs[512];
    const int t = threadIdx.x;
    hs[t] = h[t];
    hs[256 + t] = h[256 + t];
    __syncthreads();
    const int j = blockIdx.x * 256 + t;
    float a0 = 0.f, a1 = 0.f;
    #pragma unroll 8
    for (int k = 0; k < 256; ++k) {
        float w = w2[(size_t)k * SDn + j];
        a0 = fmaf(hs[k], w, a0);
        a1 = fmaf(hs[256 + k], w, a1);
    }
    const int s = j >> 7, d = j & 127;
    const int i2 = d >> 1;
    const float freq = __expf(-(float)(2 * i2) * (9.210340371976184f / 128.f));
    const float ang = (float)s * freq;
    const float pe = (d & 1) ? cosf(ang) : sinf(ang);
    const float bias = b2[j] + pe;
    const float v0 = a0 + bias;
    const float v1 = a1 + bias;
    x[j] = v0;          enc[j] = v0;
    x[SDn + j] = v1;    enc[SDn + j] = v1;
}

// ---------------------------------------------------------------------------
// Generic tiled fp32 matmul C = A @ W + bias  (optional relu)
// ---------------------------------------------------------------------------
__global__ __launch_bounds__(256) void mm64_kernel(
    const float* __restrict__ A0, const float* __restrict__ A1, const float* __restrict__ A2,
    const float* __restrict__ W0, const float* __restrict__ W1, const float* __restrict__ W2,
    const float* __restrict__ B0, const float* __restrict__ B1, const float* __restrict__ B2,
    float* __restrict__ C0, float* __restrict__ C1, float* __restrict__ C2,
    int M, int N, int K, int relu)
{
    const int z = blockIdx.z;
    const float* A = (z == 0) ? A0 : (z == 1) ? A1 : A2;
    const float* W = (z == 0) ? W0 : (z == 1) ? W1 : W2;
    const float* Bi = (z == 0) ? B0 : (z == 1) ? B1 : B2;
    float* C = (z == 0) ? C0 : (z == 1) ? C1 : C2;

    __shared__ float As[16][64];
    __shared__ float Wsh[16][64];

    const int t = threadIdx.x;
    const int tx = t & 15, ty = t >> 4;
    const int m0 = blockIdx.x * 64;
    const int n0 = blockIdx.y * 64;

    const int arow = t >> 2;
    const int acol = (t & 3) << 2;
    const int wrow = t >> 4;
    const int wcol = (t & 15) << 2;

    float acc[4][4] = {};

    for (int k0 = 0; k0 < K; k0 += 16) {
        float4 av = make_float4(0.f, 0.f, 0.f, 0.f);
        if (m0 + arow < M)
            av = *(const float4*)&A[(size_t)(m0 + arow) * K + k0 + acol];
        As[acol + 0][arow] = av.x;
        As[acol + 1][arow] = av.y;
        As[acol + 2][arow] = av.z;
        As[acol + 3][arow] = av.w;
        float4 wv = *(const float4*)&W[(size_t)(k0 + wrow) * N + n0 + wcol];
        *(float4*)&Wsh[wrow][wcol] = wv;
        __syncthreads();
        #pragma unroll
        for (int kk = 0; kk < 16; ++kk) {
            float a4[4], b4[4];
            #pragma unroll
            for (int ii = 0; ii < 4; ++ii) a4[ii] = As[kk][ty * 4 + ii];
            #pragma unroll
            for (int jj = 0; jj < 4; ++jj) b4[jj] = Wsh[kk][tx * 4 + jj];
            #pragma unroll
            for (int ii = 0; ii < 4; ++ii)
                #pragma unroll
                for (int jj = 0; jj < 4; ++jj)
                    acc[ii][jj] = fmaf(a4[ii], b4[jj], acc[ii][jj]);
        }
        __syncthreads();
    }

    #pragma unroll
    for (int ii = 0; ii < 4; ++ii) {
        const int r = m0 + ty * 4 + ii;
        if (r >= M) continue;
        #pragma unroll
        for (int jj = 0; jj < 4; ++jj) {
            const int c = n0 + tx * 4 + jj;
            float vv = acc[ii][jj] + Bi[c];
            if (relu) vv = fmaxf(vv, 0.f);
            C[(size_t)r * N + c] = vv;
        }
    }
}

// ---------------------------------------------------------------------------
// Convert fp32 Q,K,V ([B,S,128]) into bf16 MFMA-friendly buffers:
//   Qb[bh][s][16] (scaled by 1/sqrt(16)), Kb[bh][s][16], Vt[bh][d16][1824]
// ---------------------------------------------------------------------------
__global__ __launch_bounds__(256) void conv_kernel(
    const float* __restrict__ q, const float* __restrict__ k, const float* __restrict__ v,
    unsigned short* __restrict__ Qb, unsigned short* __restrict__ Kb,
    unsigned short* __restrict__ Vt)
{
    const int id = blockIdx.x * 256 + threadIdx.x;   // 0..460799
    const int s = id >> 7, c = id & 127;
    const int bq = (s >= Sn) ? 1 : 0;
    const int srow = s - bq * Sn;
    const int h = c >> 4, d = c & 15;
    const int bh = bq * 8 + h;
    const float qv = q[id] * 0.25f;
    const float kv = k[id];
    const float vv = v[id];
    const size_t o = ((size_t)bh * Sn + srow) * 16 + d;
    Qb[o] = f2bf(qv);
    Kb[o] = f2bf(kv);
    Vt[((size_t)bh * 16 + d) * VTJ + srow] = f2bf(vv);
}

// zero the j-padding region of Vt (j in [1800,1824))
__global__ __launch_bounds__(256) void zvt_kernel(unsigned short* __restrict__ Vt)
{
    const int i = blockIdx.x * 256 + threadIdx.x;   // 16*16*24 = 6144
    if (i < 16 * 16 * 24) {
        const int bhd = i / 24, jj = i % 24;
        Vt[(size_t)bhd * VTJ + Sn + jj] = 0;
    }
}

// ---------------------------------------------------------------------------
// MFMA flash attention. Block = 128 threads (2 waves), each wave = one 32-q
// tile of one (b,h). QK^T swapped (mfma(K,Q)) so q = lane&31; PV computed as
// O^T = V^T P^T so the output shares the q=lane&31 orientation and the online
// softmax rescale stays a per-lane scalar.
// MASK=1: strictly-upper mask (keep j > i), -1e9, with jt>=qt tile skipping.
// ---------------------------------------------------------------------------
template <int MASK>
__global__ __launch_bounds__(128) void flash_mfma(
    const unsigned short* __restrict__ Qb, const unsigned short* __restrict__ Kb,
    const unsigned short* __restrict__ Vt, float* __restrict__ O)
{
    const int wid = threadIdx.x >> 6;
    const int lane = threadIdx.x & 63;
    const int bh = blockIdx.y;
    const int b = bh >> 3, h = bh & 7;

    int qt;
    if (MASK) {
        qt = wid ? (NQT - 1 - (int)blockIdx.x) : (int)blockIdx.x;
        if (wid && blockIdx.x == 28) return;   // qt=28 covered by wave 0
    } else {
        qt = 2 * (int)blockIdx.x + wid;
        if (qt >= NQT) return;
    }

    const int ql = lane & 31;
    const int hi = lane >> 5;

    const int qrow = qt * 32 + ql;
    const int qr = (qrow < Sn) ? qrow : (Sn - 1);
    const short8 qf = *(const short8*)(Qb + ((size_t)bh * Sn + qr) * 16 + 8 * hi);

    const unsigned short* kbase = Kb + (size_t)bh * Sn * 16;
    const unsigned short* vbase = Vt + ((size_t)bh * 16 + (ql & 15)) * VTJ;

    f32x16 acc = (f32x16)0.0f;
    float m = -INFINITY, lsum = 0.f;

    const int jt0 = MASK ? qt : 0;

    // software pipeline: preload tile jt0
    int krow = jt0 * 32 + ql; if (krow >= Sn) krow = Sn - 1;
    short8 kf  = *(const short8*)(kbase + (size_t)krow * 16 + 8 * hi);
    short8 va  = *(const short8*)(vbase + jt0 * 32 + 8 * hi);
    short8 vb2 = *(const short8*)(vbase + jt0 * 32 + 16 + 8 * hi);

    for (int jt = jt0; jt < NQT; ++jt) {
        short8 kn = kf, van = va, vbn = vb2;
        if (jt + 1 < NQT) {
            int nrow = (jt + 1) * 32 + ql; if (nrow >= Sn) nrow = Sn - 1;
            kn  = *(const short8*)(kbase + (size_t)nrow * 16 + 8 * hi);
            van = *(const short8*)(vbase + (jt + 1) * 32 + 8 * hi);
            vbn = *(const short8*)(vbase + (jt + 1) * 32 + 16 + 8 * hi);
        }

        f32x16 sc = __builtin_amdgcn_mfma_f32_32x32x16_bf16(kf, qf, (f32x16)0.0f, 0, 0, 0);

        float sv[16];
        #pragma unroll
        for (int r = 0; r < 16; ++r) sv[r] = sc[r];

        if (MASK && jt == qt) {
            #pragma unroll
            for (int r = 0; r < 16; ++r) {
                const int jl = ((r & 3) + 8 * (r >> 2)) + 4 * hi;
                if (!(jl > ql)) sv[r] = -1e9f;
            }
        }
        if (jt == NQT - 1) {
            #pragma unroll
            for (int r = 0; r < 16; ++r) {
                const int jg = (NQT - 1) * 32 + ((r & 3) + 8 * (r >> 2)) + 4 * hi;
                if (jg >= Sn) sv[r] = -1e30f;
            }
        }

        float tmax = sv[0];
        #pragma unroll
        for (int r = 1; r < 16; ++r) tmax = fmaxf(tmax, sv[r]);
        tmax = fmaxf(tmax, __shfl_xor(tmax, 32));
        const float mnew = fmaxf(m, tmax);
        const float corr = __expf(m - mnew);
        m = mnew;
        lsum *= corr;
        #pragma unroll
        for (int r = 0; r < 16; ++r) acc[r] *= corr;

        float p[16];
        float ps = 0.f;
        #pragma unroll
        for (int r = 0; r < 16; ++r) { p[r] = __expf(sv[r] - mnew); ps += p[r]; }
        lsum += ps;

        // pack P -> bf16 and redistribute within the lane/lane+32 pair
        const u32 w01 = cvtpk_bf16(p[0],  p[1]),  w23 = cvtpk_bf16(p[2],  p[3]);
        const u32 w45 = cvtpk_bf16(p[4],  p[5]),  w67 = cvtpk_bf16(p[6],  p[7]);
        const u32 v01 = cvtpk_bf16(p[8],  p[9]),  v23 = cvtpk_bf16(p[10], p[11]);
        const u32 v45 = cvtpk_bf16(p[12], p[13]), v67 = cvtpk_bf16(p[14], p[15]);
        const u32 x01 = (u32)__shfl_xor((int)w01, 32);
        const u32 x23 = (u32)__shfl_xor((int)w23, 32);
        const u32 x45 = (u32)__shfl_xor((int)w45, 32);
        const u32 x67 = (u32)__shfl_xor((int)w67, 32);
        const u32 y01 = (u32)__shfl_xor((int)v01, 32);
        const u32 y23 = (u32)__shfl_xor((int)v23, 32);
        const u32 y45 = (u32)__shfl_xor((int)v45, 32);
        const u32 y67 = (u32)__shfl_xor((int)v67, 32);

        union { u32 u[4]; short8 s; } B0c, B1c;
        if (hi == 0) {
            B0c.u[0] = w01; B0c.u[1] = w23; B0c.u[2] = x01; B0c.u[3] = x23;
            B1c.u[0] = v01; B1c.u[1] = v23; B1c.u[2] = y01; B1c.u[3] = y23;
        } else {
            B0c.u[0] = x45; B0c.u[1] = x67; B0c.u[2] = w45; B0c.u[3] = w67;
            B1c.u[0] = y45; B1c.u[1] = y67; B1c.u[2] = v45; B1c.u[3] = v67;
        }

        acc = __builtin_amdgcn_mfma_f32_32x32x16_bf16(va,  B0c.s, acc, 0, 0, 0);
        acc = __builtin_amdgcn_mfma_f32_32x32x16_bf16(vb2, B1c.s, acc, 0, 0, 0);

        kf = kn; va = van; vb2 = vbn;
    }

    if (qrow < Sn) {
        const float ltot = lsum + __shfl_xor(lsum, 32);
        float inv = 1.f / ltot;
        if (MASK && qrow == Sn - 1) inv = 0.f;   // zeroed; fix1799 adds mean(V)
        float* op = O + ((size_t)(b * Sn + qrow)) * Dn + h * DKn;
        float4 o0, o1;
        o0.x = acc[0] * inv; o0.y = acc[1] * inv; o0.z = acc[2] * inv; o0.w = acc[3] * inv;
        o1.x = acc[4] * inv; o1.y = acc[5] * inv; o1.z = acc[6] * inv; o1.w = acc[7] * inv;
        *(float4*)(op + 4 * hi)     = o0;   // d = 0..3  (+4*hi)
        *(float4*)(op + 8 + 4 * hi) = o1;   // d = 8..11 (+4*hi)
    }
}

// ---------------------------------------------------------------------------
// Reference's fully-masked last row: softmax(all -1e9) = uniform -> mean of V.
// flash_mfma<1> stored zeros at row 1799; accumulate mean via atomics.
// ---------------------------------------------------------------------------
__global__ __launch_bounds__(128) void fix1799_kernel(
    const float* __restrict__ v, float* __restrict__ O)
{
    const int b = blockIdx.x, ch = blockIdx.y;
    const int c = threadIdx.x;
    const int r0 = ch * 113;
    const int r1 = (r0 + 113 < Sn) ? r0 + 113 : Sn;
    float s = 0.f;
    for (int r = r0; r < r1; ++r) s += v[((size_t)(b * Sn + r)) * Dn + c];
    atomicAdd(&O[((size_t)(b * Sn + (Sn - 1))) * Dn + c], s * (1.f / (float)Sn));
}

// ---------------------------------------------------------------------------
// y = LayerNorm(x + a) * g + b
// ---------------------------------------------------------------------------
__global__ __launch_bounds__(64) void ln_kernel(
    const float* __restrict__ X, const float* __restrict__ A,
    const float* __restrict__ g, const float* __restrict__ bb,
    float* __restrict__ Y)
{
    const int row = blockIdx.x;
    const int d = threadIdx.x;
    const size_t base = (size_t)row * 128;
    float v0 = X[base + d] + A[base + d];
    float v1 = X[base + d + 64] + A[base + d + 64];
    float sum = v0 + v1;
    #pragma unroll
    for (int off = 32; off > 0; off >>= 1) sum += __shfl_xor(sum, off);
    const float mu = sum * (1.f / 128.f);
    const float d0 = v0 - mu, d1 = v1 - mu;
    float vs = d0 * d0 + d1 * d1;
    #pragma unroll
    for (int off = 32; off > 0; off >>= 1) vs += __shfl_xor(vs, off);
    const float inv = rsqrtf(vs * (1.f / 128.f) + 1e-5f);
    Y[base + d] = d0 * inv * g[d] + bb[d];
    Y[base + d + 64] = d1 * inv * g[d + 64] + bb[d + 64];
}

// ---------------------------------------------------------------------------
// logits = x @ out_w + out_b
// ---------------------------------------------------------------------------
__global__ __launch_bounds__(256) void out_kernel(
    const float* __restrict__ X, const float* __restrict__ W,
    const float* __restrict__ bb, float* __restrict__ out)
{
    const int t = threadIdx.x;
    const int n = t & 15;
    const int r = blockIdx.x * 16 + (t >> 4);
    if (r >= BSn) return;
    float acc = 0.f;
    #pragma unroll 8
    for (int k = 0; k < 128; ++k)
        acc = fmaf(X[(size_t)r * 128 + k], W[k * 16 + n], acc);
    out[(size_t)r * 16 + n] = acc + bb[n];
}

// ---------------------------------------------------------------------------
extern "C" void kernel_launch(void* const* d_in, const int* in_sizes, int n_in,
                              void* d_out, int out_size, void* d_ws, size_t ws_size,
                              hipStream_t stream)
{
    const float* latent = (const float*)d_in[0];
    const float* lp_w1  = (const float*)d_in[1];
    const float* lp_b1  = (const float*)d_in[2];
    const float* lp_w2  = (const float*)d_in[3];
    const float* lp_b2  = (const float*)d_in[4];
    const float* out_w  = (const float*)d_in[5];
    const float* out_b  = (const float*)d_in[6];
    const float* sa_wq = (const float*)d_in[7];  const float* sa_bq = (const float*)d_in[8];
    const float* sa_wk = (const float*)d_in[9];  const float* sa_bk = (const float*)d_in[10];
    const float* sa_wv = (const float*)d_in[11]; const float* sa_bv = (const float*)d_in[12];
    const float* sa_wo = (const float*)d_in[13]; const float* sa_bo = (const float*)d_in[14];
    const float* ca_wq = (const float*)d_in[15]; const float* ca_bq = (const float*)d_in[16];
    const float* ca_wk = (const float*)d_in[17]; const float* ca_bk = (const float*)d_in[18];
    const float* ca_wv = (const float*)d_in[19]; const float* ca_bv = (const float*)d_in[20];
    const float* ca_wo = (const float*)d_in[21]; const float* ca_bo = (const float*)d_in[22];
    const float* ff_w1 = (const float*)d_in[23]; const float* ff_b1 = (const float*)d_in[24];
    const float* ff_w2 = (const float*)d_in[25]; const float* ff_b2 = (const float*)d_in[26];
    const float* ln1g = (const float*)d_in[27]; const float* ln1b = (const float*)d_in[28];
    const float* ln2g = (const float*)d_in[29]; const float* ln2b = (const float*)d_in[30];
    const float* ln3g = (const float*)d_in[31]; const float* ln3b = (const float*)d_in[32];

    float* ws = (float*)d_ws;
    float* x    = ws + 0 * 460800;
    float* enc  = ws + 1 * 460800;
    float* qb   = ws + 2 * 460800;
    float* kb   = ws + 3 * 460800;
    float* vb   = ws + 4 * 460800;
    float* t0   = ws + 5 * 460800;
    float* t1   = ws + 6 * 460800;
    float* hff  = ws + 7 * 460800;             // 3600*512 floats
    float* hlat = ws + 7 * 460800 + 1843200;   // 512 floats
    // bf16 buffers (ushort), 16B-aligned float offsets
    unsigned short* Qb = (unsigned short*)(ws + 5069312);           // 460800 ushorts
    unsigned short* Kb = (unsigned short*)(ws + 5069312 + 230400);
    unsigned short* Vt = (unsigned short*)(ws + 5069312 + 460800);  // 16*16*1824 ushorts

    lat_h_kernel<<<dim3(2), dim3(256), 0, stream>>>(latent, lp_w1, lp_b1, hlat);
    dec_kernel<<<dim3(900), dim3(256), 0, stream>>>(hlat, lp_w2, lp_b2, x, enc);
    zvt_kernel<<<dim3(24), dim3(256), 0, stream>>>(Vt);

    const dim3 thr(256);
    const dim3 gProj(57, 2, 1), gQKV(57, 2, 3), gFF1(57, 8, 1);
    const dim3 gFlash(29, 16), tFlash(128);

    for (int i = 0; i < Ln; ++i) {
        const size_t wOff = (size_t)i * 128 * 128;
        const size_t bOff = (size_t)i * 128;
        const size_t fOff = (size_t)i * 128 * 512;
        const size_t f1b  = (size_t)i * 512;

        // ---- self attention ----
        mm64_kernel<<<gQKV, thr, 0, stream>>>(
            x, x, x,
            sa_wq + wOff, sa_wk + wOff, sa_wv + wOff,
            sa_bq + bOff, sa_bk + bOff, sa_bv + bOff,
            qb, kb, vb, BSn, 128, 128, 0);
        conv_kernel<<<dim3(1800), thr, 0, stream>>>(qb, kb, vb, Qb, Kb, Vt);
        flash_mfma<1><<<gFlash, tFlash, 0, stream>>>(Qb, Kb, Vt, t0);
        fix1799_kernel<<<dim3(2, 16), dim3(128), 0, stream>>>(vb, t0);
        mm64_kernel<<<gProj, thr, 0, stream>>>(
            t0, t0, t0, sa_wo + wOff, sa_wo + wOff, sa_wo + wOff,
            sa_bo + bOff, sa_bo + bOff, sa_bo + bOff,
            t1, t1, t1, BSn, 128, 128, 0);
        ln_kernel<<<dim3(BSn), dim3(64), 0, stream>>>(x, t1, ln1g + bOff, ln1b + bOff, x);

        // ---- cross attention (K/V from enc) ----
        mm64_kernel<<<gQKV, thr, 0, stream>>>(
            x, enc, enc,
            ca_wq + wOff, ca_wk + wOff, ca_wv + wOff,
            ca_bq + bOff, ca_bk + bOff, ca_bv + bOff,
            qb, kb, vb, BSn, 128, 128, 0);
        conv_kernel<<<dim3(1800), thr, 0, stream>>>(qb, kb, vb, Qb, Kb, Vt);
        flash_mfma<0><<<gFlash, tFlash, 0, stream>>>(Qb, Kb, Vt, t0);
        mm64_kernel<<<gProj, thr, 0, stream>>>(
            t0, t0, t0, ca_wo + wOff, ca_wo + wOff, ca_wo + wOff,
            ca_bo + bOff, ca_bo + bOff, ca_bo + bOff,
            t1, t1, t1, BSn, 128, 128, 0);
        ln_kernel<<<dim3(BSn), dim3(64), 0, stream>>>(x, t1, ln2g + bOff, ln2b + bOff, x);

        // ---- ffn ----
        mm64_kernel<<<gFF1, thr, 0, stream>>>(
            x, x, x, ff_w1 + fOff, ff_w1 + fOff, ff_w1 + fOff,
            ff_b1 + f1b, ff_b1 + f1b, ff_b1 + f1b,
            hff, hff, hff, BSn, DFFn, 128, 1);
        mm64_kernel<<<gProj, thr, 0, stream>>>(
            hff, hff, hff, ff_w2 + fOff, ff_w2 + fOff, ff_w2 + fOff,
            ff_b2 + bOff, ff_b2 + bOff, ff_b2 + bOff,
            t1, t1, t1, BSn, 128, DFFn, 0);
        ln_kernel<<<dim3(BSn), dim3(64), 0, stream>>>(x, t1, ln3g + bOff, ln3b + bOff, x);
    }

    out_kernel<<<dim3(225), dim3(256), 0, stream>>>(x, out_w, out_b, (float*)d_out);
}

// Round 3
// 981.056 us; speedup vs baseline: 2.2690x; 1.4071x over previous
//
#include <hip/hip_runtime.h>
#include <hip/hip_bf16.h>
#include <math.h>

// Problem constants
#define Bn   2
#define Sn   1800
#define Dn   128
#define Hn   8
#define DKn  16
#define DFFn 512
#define Ln   6
#define Vn   16
#define LATn 1024
#define BSn  3600        // B*S
#define SDn  230400      // S*D
#define NQT  57          // ceil(1800/32)
#define VTJ  1824        // padded j-dim of transposed V
#define MPAD 3712        // padded row count for bf16 activation buffers

typedef __attribute__((ext_vector_type(8))) short short8;   // 8 bf16 = 4 VGPR
typedef __attribute__((ext_vector_type(16))) float f32x16;
typedef unsigned int u32;
typedef unsigned short u16;

// MFMA 32x32x16 C/D layout: row = (reg&3) + 8*(reg>>2) + 4*hi, col = lane&31
#define ROWMAP(r, hi) (((r) & 3) + 8 * ((r) >> 2) + 4 * (hi))
// V-column permutation so PV's B-fragment needs no cross-lane exchange:
// slot pos holds actual j = g(pos); g is an involution (bit2 <-> bit3)
#define GPERM(sl) (((sl) & 3) + (((sl) & 4) << 1) + (((sl) & 8) >> 1) + ((sl) & 16))

__device__ inline u32 cvtpk_bf16(float a, float b) {
    u32 r;
    asm("v_cvt_pk_bf16_f32 %0, %1, %2" : "=v"(r) : "v"(a), "v"(b));
    return r;
}

__device__ inline u16 f2bf(float f) {
    union { float f; u32 u; } x; x.f = f;
    u32 r = (x.u + 0x7FFFu + ((x.u >> 16) & 1u)) >> 16;
    return (u16)r;
}

__device__ inline float bf2f(u16 v) {
    union { u32 u; float f; } x; x.u = ((u32)v) << 16;
    return x.f;
}

// ---------------------------------------------------------------------------
// Weight conversion: 8 square mats [6][128][128] fp32 -> bf16 transposed
// dst[l][n][k] = src[l][k][n].  Coalesced writes, strided reads (one-time).
// ---------------------------------------------------------------------------
__global__ __launch_bounds__(256) void wconv8_kernel(
    const float* __restrict__ s0, const float* __restrict__ s1,
    const float* __restrict__ s2, const float* __restrict__ s3,
    const float* __restrict__ s4, const float* __restrict__ s5,
    const float* __restrict__ s6, const float* __restrict__ s7,
    u16* __restrict__ d0, u16* __restrict__ d1, u16* __restrict__ d2,
    u16* __restrict__ d3, u16* __restrict__ d4, u16* __restrict__ d5,
    u16* __restrict__ d6, u16* __restrict__ d7)
{
    const int z = blockIdx.z;
    const float* src = (z == 0) ? s0 : (z == 1) ? s1 : (z == 2) ? s2 : (z == 3) ? s3
                     : (z == 4) ? s4 : (z == 5) ? s5 : (z == 6) ? s6 : s7;
    u16* dst = (z == 0) ? d0 : (z == 1) ? d1 : (z == 2) ? d2 : (z == 3) ? d3
             : (z == 4) ? d4 : (z == 5) ? d5 : (z == 6) ? d6 : d7;
    const int id = blockIdx.x * 256 + threadIdx.x;   // < 6*16384
    const int l = id >> 14, rem = id & 16383;
    const int n = rem >> 7, k = rem & 127;
    dst[id] = f2bf(src[l * 16384 + k * 128 + n]);
}

// generic: dst[l][n][k] = src[l][k][n], K = 1<<logK (contraction), N = 1<<logN
__global__ __launch_bounds__(256) void wconvg_kernel(
    const float* __restrict__ src, u16* __restrict__ dst, int logK, int logN)
{
    const int id = blockIdx.x * 256 + threadIdx.x;
    const int kn = 1 << (logK + logN);
    const int l = id >> (logK + logN);
    const int rem = id & (kn - 1);
    const int n = rem >> logK, k = rem & ((1 << logK) - 1);
    dst[id] = f2bf(src[(size_t)l * kn + (k << logN) + n]);
}

// zero V^T tile-56 slots (positions 1792..1823) so unwritten slots are 0
__global__ __launch_bounds__(256) void zvt_kernel(u16* __restrict__ Vt)
{
    const int id = blockIdx.x * 256 + threadIdx.x;   // < 256*32 = 8192
    const int row = id >> 5, pos = id & 31;
    Vt[(size_t)row * VTJ + 1792 + pos] = 0;
}

// ---------------------------------------------------------------------------
// h = relu(latent @ lp_w1 + lp_b1)   [2, 256]
// ---------------------------------------------------------------------------
__global__ __launch_bounds__(256) void lat_h_kernel(
    const float* __restrict__ latent, const float* __restrict__ w1,
    const float* __restrict__ b1, float* __restrict__ h)
{
    __shared__ float ls[LATn];
    const int b = blockIdx.x;
    const int t = threadIdx.x;
    for (int k = t; k < LATn; k += 256) ls[k] = latent[b * LATn + k];
    __syncthreads();
    float acc = 0.f;
    #pragma unroll 8
    for (int k = 0; k < LATn; ++k) acc = fmaf(ls[k], w1[(size_t)k * 256 + t], acc);
    h[b * 256 + t] = fmaxf(acc + b1[t], 0.f);
}

// ---------------------------------------------------------------------------
// dec = h @ lp_w2 + lp_b2 + pos_encoding ; writes fp32 x and bf16 xb, encb
// ---------------------------------------------------------------------------
__global__ __launch_bounds__(256) void dec_kernel(
    const float* __restrict__ h, const float* __restrict__ w2,
    const float* __restrict__ b2, float* __restrict__ x,
    u16* __restrict__ xb, u16* __restrict__ encb)
{
    __shared__ float hs[512];
    const int t = threadIdx.x;
    hs[t] = h[t];
    hs[256 + t] = h[256 + t];
    __syncthreads();
    const int j = blockIdx.x * 256 + t;
    float a0 = 0.f, a1 = 0.f;
    #pragma unroll 8
    for (int k = 0; k < 256; ++k) {
        float w = w2[(size_t)k * SDn + j];
        a0 = fmaf(hs[k], w, a0);
        a1 = fmaf(hs[256 + k], w, a1);
    }
    const int s = j >> 7, d = j & 127;
    const int i2 = d >> 1;
    const float freq = __expf(-(float)(2 * i2) * (9.210340371976184f / 128.f));
    const float ang = (float)s * freq;
    const float pe = (d & 1) ? cosf(ang) : sinf(ang);
    const float bias = b2[j] + pe;
    const float v0 = a0 + bias;
    const float v1 = a1 + bias;
    x[j] = v0;
    x[SDn + j] = v1;
    xb[j] = f2bf(v0);    xb[SDn + j] = f2bf(v1);
    encb[j] = f2bf(v0);  encb[SDn + j] = f2bf(v1);
}

// ---------------------------------------------------------------------------
// QKV projection, bf16 MFMA, fused bf16 re-layout epilogue.
// grid (57, 1, 3): z=0 Q (scaled 0.25), z=1 K, z=2 V (permuted transpose).
// Block 256 = 4 waves: wave w -> m-tile (w&1), n-half (w>>1).
// ---------------------------------------------------------------------------
__global__ __launch_bounds__(256) void mm_qkv_kernel(
    const u16* __restrict__ Aq, const u16* __restrict__ Akv,
    const u16* __restrict__ Wq, const u16* __restrict__ Wk, const u16* __restrict__ Wv,
    const float* __restrict__ bq, const float* __restrict__ bk, const float* __restrict__ bv,
    u16* __restrict__ Qb, u16* __restrict__ Kb, u16* __restrict__ Vt)
{
    const int z = blockIdx.z;
    const u16* A = (z == 0) ? Aq : Akv;
    const u16* W = (z == 0) ? Wq : (z == 1) ? Wk : Wv;
    const float* Bi = (z == 0) ? bq : (z == 1) ? bk : bv;

    const int w = threadIdx.x >> 6;
    const int lane = threadIdx.x & 63;
    const int ql = lane & 31, hi = lane >> 5;
    const int m0 = blockIdx.x * 64 + (w & 1) * 32;
    const int nh = (w >> 1) * 64;

    f32x16 acc0 = (f32x16)0.0f, acc1 = (f32x16)0.0f;
    const size_t arow = (size_t)(m0 + ql) * 128;

    #pragma unroll
    for (int kk = 0; kk < 8; ++kk) {
        const short8 a = *(const short8*)(A + arow + kk * 16 + 8 * hi);
        const short8 b0 = *(const short8*)(W + (size_t)(nh + ql) * 128 + kk * 16 + 8 * hi);
        const short8 b1 = *(const short8*)(W + (size_t)(nh + 32 + ql) * 128 + kk * 16 + 8 * hi);
        acc0 = __builtin_amdgcn_mfma_f32_32x32x16_bf16(a, b0, acc0, 0, 0, 0);
        acc1 = __builtin_amdgcn_mfma_f32_32x32x16_bf16(a, b1, acc1, 0, 0, 0);
    }

    #pragma unroll
    for (int j = 0; j < 2; ++j) {
        const int n = nh + j * 32 + ql;
        const float bv_ = Bi[n];
        const int h = n >> 4, d = n & 15;
        #pragma unroll
        for (int r = 0; r < 16; ++r) {
            const int m = m0 + ROWMAP(r, hi);
            if (m >= BSn) continue;
            float v = (j ? acc1[r] : acc0[r]) + bv_;
            const int bq_ = (m >= Sn) ? 1 : 0;
            const int s = m - bq_ * Sn;
            const int bh = bq_ * 8 + h;
            if (z == 0) {
                Qb[((size_t)bh * Sn + s) * 16 + d] = f2bf(v * 0.25f);
            } else if (z == 1) {
                Kb[((size_t)bh * Sn + s) * 16 + d] = f2bf(v);
            } else {
                const int jt = s >> 5, sl = s & 31;
                Vt[((size_t)bh * 16 + d) * VTJ + jt * 32 + GPERM(sl)] = f2bf(v);
            }
        }
    }
}

// ---------------------------------------------------------------------------
// GEMM + bias + residual + LayerNorm fused.  A bf16 [MPAD][K], Wt bf16 [128][K].
// grid 57, block 256 (4 waves, BM=64, BN=128). KS = K/16.
// ---------------------------------------------------------------------------
template <int KS>
__global__ __launch_bounds__(256) void mm_oln_kernel(
    const u16* __restrict__ A, const u16* __restrict__ Wt,
    const float* __restrict__ Bi, const float* __restrict__ xres,
    const float* __restrict__ g, const float* __restrict__ bb,
    float* __restrict__ X, u16* __restrict__ XB)
{
    __shared__ float ls[64 * 132];
    __shared__ float mus[64], invs[64];

    const int t = threadIdx.x;
    const int w = t >> 6;
    const int lane = t & 63;
    const int ql = lane & 31, hi = lane >> 5;
    const int K = KS * 16;
    const int mt = (w & 1) * 32;
    const int nh = (w >> 1) * 64;
    const int m0 = blockIdx.x * 64;

    f32x16 acc0 = (f32x16)0.0f, acc1 = (f32x16)0.0f;
    const size_t arow = (size_t)(m0 + mt + ql) * K;

    #pragma unroll
    for (int kk = 0; kk < KS; ++kk) {
        const short8 a = *(const short8*)(A + arow + kk * 16 + 8 * hi);
        const short8 b0 = *(const short8*)(Wt + (size_t)(nh + ql) * K + kk * 16 + 8 * hi);
        const short8 b1 = *(const short8*)(Wt + (size_t)(nh + 32 + ql) * K + kk * 16 + 8 * hi);
        acc0 = __builtin_amdgcn_mfma_f32_32x32x16_bf16(a, b0, acc0, 0, 0, 0);
        acc1 = __builtin_amdgcn_mfma_f32_32x32x16_bf16(a, b1, acc1, 0, 0, 0);
    }

    #pragma unroll
    for (int j = 0; j < 2; ++j) {
        const int n = nh + j * 32 + ql;
        const float bv_ = Bi[n];
        #pragma unroll
        for (int r = 0; r < 16; ++r) {
            const int row = mt + ROWMAP(r, hi);
            const int gm = m0 + row;
            float v = (j ? acc1[r] : acc0[r]) + bv_;
            if (gm < BSn) v += xres[(size_t)gm * 128 + n];
            ls[row * 132 + n] = v;
        }
    }
    __syncthreads();

    // stats: 4 threads per row, 32 cols each
    {
        const int row = t >> 2, q = t & 3;
        float s1 = 0.f, s2 = 0.f;
        const float* lr = &ls[row * 132 + q * 32];
        #pragma unroll
        for (int c = 0; c < 32; c += 4) {
            const float4 v = *(const float4*)&lr[c];
            s1 += v.x + v.y + v.z + v.w;
            s2 += v.x * v.x + v.y * v.y + v.z * v.z + v.w * v.w;
        }
        s1 += __shfl_xor(s1, 1); s2 += __shfl_xor(s2, 1);
        s1 += __shfl_xor(s1, 2); s2 += __shfl_xor(s2, 2);
        const float mu = s1 * (1.f / 128.f);
        const float var = s2 * (1.f / 128.f) - mu * mu;
        if (q == 0) { mus[row] = mu; invs[row] = rsqrtf(var + 1e-5f); }
    }
    __syncthreads();

    // write: 64 rows x 32 float4-groups
    #pragma unroll
    for (int it = 0; it < 8; ++it) {
        const int idx = it * 256 + t;
        const int row = idx >> 5, cg = (idx & 31) * 4;
        const int gm = m0 + row;
        if (gm >= BSn) continue;
        const float4 v = *(const float4*)&ls[row * 132 + cg];
        const float mu = mus[row], inv = invs[row];
        const float4 gv = *(const float4*)&g[cg];
        const float4 bv_ = *(const float4*)&bb[cg];
        float4 y;
        y.x = (v.x - mu) * inv * gv.x + bv_.x;
        y.y = (v.y - mu) * inv * gv.y + bv_.y;
        y.z = (v.z - mu) * inv * gv.z + bv_.z;
        y.w = (v.w - mu) * inv * gv.w + bv_.w;
        *(float4*)&X[(size_t)gm * 128 + cg] = y;
        uint2 u;
        u.x = cvtpk_bf16(y.x, y.y);
        u.y = cvtpk_bf16(y.z, y.w);
        *(uint2*)&XB[(size_t)gm * 128 + cg] = u;
    }
}

// ---------------------------------------------------------------------------
// FF1: h = relu(x @ W1 + b1), bf16 out [MPAD][512].  grid (57, 4).
// ---------------------------------------------------------------------------
__global__ __launch_bounds__(256) void mm_ff1_kernel(
    const u16* __restrict__ A, const u16* __restrict__ Wt,
    const float* __restrict__ Bi, u16* __restrict__ Hb)
{
    const int t = threadIdx.x;
    const int w = t >> 6;
    const int lane = t & 63;
    const int ql = lane & 31, hi = lane >> 5;
    const int m0 = blockIdx.x * 64 + (w & 1) * 32;
    const int n0 = blockIdx.y * 128 + (w >> 1) * 64;

    f32x16 acc0 = (f32x16)0.0f, acc1 = (f32x16)0.0f;
    const size_t arow = (size_t)(m0 + ql) * 128;

    #pragma unroll
    for (int kk = 0; kk < 8; ++kk) {
        const short8 a = *(const short8*)(A + arow + kk * 16 + 8 * hi);
        const short8 b0 = *(const short8*)(Wt + (size_t)(n0 + ql) * 128 + kk * 16 + 8 * hi);
        const short8 b1 = *(const short8*)(Wt + (size_t)(n0 + 32 + ql) * 128 + kk * 16 + 8 * hi);
        acc0 = __builtin_amdgcn_mfma_f32_32x32x16_bf16(a, b0, acc0, 0, 0, 0);
        acc1 = __builtin_amdgcn_mfma_f32_32x32x16_bf16(a, b1, acc1, 0, 0, 0);
    }

    #pragma unroll
    for (int j = 0; j < 2; ++j) {
        const int n = n0 + j * 32 + ql;
        const float bv_ = Bi[n];
        #pragma unroll
        for (int r = 0; r < 16; ++r) {
            const int m = m0 + ROWMAP(r, hi);
            const float v = fmaxf((j ? acc1[r] : acc0[r]) + bv_, 0.f);
            Hb[(size_t)m * 512 + n] = f2bf(v);
        }
    }
}

// ---------------------------------------------------------------------------
// vmean: write attention output row 1799 = mean over s of V (uniform softmax
// over the fully-masked last row).  grid 256 (= 16 bh * 16 d), 64 threads.
// ---------------------------------------------------------------------------
__global__ __launch_bounds__(64) void vmean_kernel(
    const u16* __restrict__ Vt, u16* __restrict__ Ob)
{
    const int id = blockIdx.x;
    const int bh = id >> 4, d = id & 15;
    const int b = bh >> 3, h = bh & 7;
    const u16* row = Vt + ((size_t)bh * 16 + d) * VTJ;
    const int lane = threadIdx.x;
    float s = 0.f;
    for (int i = lane; i < VTJ; i += 64) s += bf2f(row[i]);  // pad slots are 0
    #pragma unroll
    for (int off = 1; off < 64; off <<= 1) s += __shfl_xor(s, off);
    if (lane == 0)
        Ob[((size_t)(b * Sn + (Sn - 1))) * 128 + h * 16 + d] = f2bf(s * (1.f / (float)Sn));
}

// ---------------------------------------------------------------------------
// MFMA flash attention.  One wave per block, grid (57, 16).
// Swapped QK^T (q = lane&31); PV via permuted V^T so the P->B-fragment pack
// needs no cross-lane exchange.  Output bf16 [B*S][128].
// MASK=1: strictly-upper mask (keep j > i), -1e9, tiles jt >= qt only;
// row 1799 (fully masked) is written by vmean_kernel instead.
// ---------------------------------------------------------------------------
template <int MASK>
__global__ __launch_bounds__(64) void flash_mfma(
    const u16* __restrict__ Qb, const u16* __restrict__ Kb,
    const u16* __restrict__ Vt, u16* __restrict__ Ob)
{
    const int lane = threadIdx.x;
    const int ql = lane & 31, hi = lane >> 5;
    const int qt = blockIdx.x;
    const int bh = blockIdx.y;
    const int b = bh >> 3, h = bh & 7;

    const int qrow = qt * 32 + ql;
    const int qr = (qrow < Sn) ? qrow : (Sn - 1);
    const short8 qf = *(const short8*)(Qb + ((size_t)bh * Sn + qr) * 16 + 8 * hi);
    const u16* kbase = Kb + (size_t)bh * Sn * 16;
    const u16* vbase = Vt + ((size_t)bh * 16 + (ql & 15)) * VTJ;

    f32x16 acc = (f32x16)0.0f;
    float m = -INFINITY, lsum = 0.f;
    const int jt0 = MASK ? qt : 0;

    int krow = jt0 * 32 + ql; if (krow >= Sn) krow = Sn - 1;
    short8 kf  = *(const short8*)(kbase + (size_t)krow * 16 + 8 * hi);
    short8 va  = *(const short8*)(vbase + jt0 * 32 + 8 * hi);
    short8 vb2 = *(const short8*)(vbase + jt0 * 32 + 16 + 8 * hi);

    for (int jt = jt0; jt < NQT; ++jt) {
        short8 kn = kf, van = va, vbn = vb2;
        if (jt + 1 < NQT) {
            int nrow = (jt + 1) * 32 + ql; if (nrow >= Sn) nrow = Sn - 1;
            kn  = *(const short8*)(kbase + (size_t)nrow * 16 + 8 * hi);
            van = *(const short8*)(vbase + (jt + 1) * 32 + 8 * hi);
            vbn = *(const short8*)(vbase + (jt + 1) * 32 + 16 + 8 * hi);
        }

        const f32x16 sc = __builtin_amdgcn_mfma_f32_32x32x16_bf16(kf, qf, (f32x16)0.0f, 0, 0, 0);

        float sv[16];
        #pragma unroll
        for (int r = 0; r < 16; ++r) sv[r] = sc[r];

        if (MASK && jt == qt) {
            #pragma unroll
            for (int r = 0; r < 16; ++r)
                if (!(ROWMAP(r, hi) > ql)) sv[r] = -1e9f;
        }
        if (jt == NQT - 1) {
            #pragma unroll
            for (int r = 0; r < 16; ++r)
                if (1792 + ROWMAP(r, hi) >= Sn) sv[r] = -1e30f;
        }

        float tmax = sv[0];
        #pragma unroll
        for (int r = 1; r < 16; ++r) tmax = fmaxf(tmax, sv[r]);
        tmax = fmaxf(tmax, __shfl_xor(tmax, 32));
        const float mnew = fmaxf(m, tmax);
        const float corr = __expf(m - mnew);
        m = mnew;
        lsum *= corr;
        #pragma unroll
        for (int r = 0; r < 16; ++r) acc[r] *= corr;

        float p[16];
        float ps = 0.f;
        #pragma unroll
        for (int r = 0; r < 16; ++r) { p[r] = __expf(sv[r] - mnew); ps += p[r]; }
        lsum += ps;

        // B-fragments directly from lane-local p[] (V columns pre-permuted)
        union { u32 u[4]; short8 s; } B0c, B1c;
        B0c.u[0] = cvtpk_bf16(p[0],  p[1]);  B0c.u[1] = cvtpk_bf16(p[2],  p[3]);
        B0c.u[2] = cvtpk_bf16(p[4],  p[5]);  B0c.u[3] = cvtpk_bf16(p[6],  p[7]);
        B1c.u[0] = cvtpk_bf16(p[8],  p[9]);  B1c.u[1] = cvtpk_bf16(p[10], p[11]);
        B1c.u[2] = cvtpk_bf16(p[12], p[13]); B1c.u[3] = cvtpk_bf16(p[14], p[15]);

        acc = __builtin_amdgcn_mfma_f32_32x32x16_bf16(va,  B0c.s, acc, 0, 0, 0);
        acc = __builtin_amdgcn_mfma_f32_32x32x16_bf16(vb2, B1c.s, acc, 0, 0, 0);

        kf = kn; va = van; vb2 = vbn;
    }

    if (qrow < Sn && !(MASK && qrow == Sn - 1)) {
        const float ltot = lsum + __shfl_xor(lsum, 32);
        const float inv = 1.f / ltot;
        u16* op = Ob + ((size_t)(b * Sn + qrow)) * 128 + h * 16;
        uint2 u0, u1;
        u0.x = cvtpk_bf16(acc[0] * inv, acc[1] * inv);
        u0.y = cvtpk_bf16(acc[2] * inv, acc[3] * inv);
        u1.x = cvtpk_bf16(acc[4] * inv, acc[5] * inv);
        u1.y = cvtpk_bf16(acc[6] * inv, acc[7] * inv);
        *(uint2*)(op + 4 * hi) = u0;        // d = 4*hi .. 4*hi+3
        *(uint2*)(op + 8 + 4 * hi) = u1;    // d = 8+4*hi .. 8+4*hi+3
    }
}

// ---------------------------------------------------------------------------
// logits = x @ out_w + out_b   [3600,128]@[128,16]  (fp32)
// ---------------------------------------------------------------------------
__global__ __launch_bounds__(256) void out_kernel(
    const float* __restrict__ X, const float* __restrict__ W,
    const float* __restrict__ bb, float* __restrict__ out)
{
    const int t = threadIdx.x;
    const int n = t & 15;
    const int r = blockIdx.x * 16 + (t >> 4);
    if (r >= BSn) return;
    float acc = 0.f;
    #pragma unroll 8
    for (int k = 0; k < 128; ++k)
        acc = fmaf(X[(size_t)r * 128 + k], W[k * 16 + n], acc);
    out[(size_t)r * 16 + n] = acc + bb[n];
}

// ---------------------------------------------------------------------------
extern "C" void kernel_launch(void* const* d_in, const int* in_sizes, int n_in,
                              void* d_out, int out_size, void* d_ws, size_t ws_size,
                              hipStream_t stream)
{
    const float* latent = (const float*)d_in[0];
    const float* lp_w1  = (const float*)d_in[1];
    const float* lp_b1  = (const float*)d_in[2];
    const float* lp_w2  = (const float*)d_in[3];
    const float* lp_b2  = (const float*)d_in[4];
    const float* out_w  = (const float*)d_in[5];
    const float* out_b  = (const float*)d_in[6];
    const float* sa_wq = (const float*)d_in[7];  const float* sa_bq = (const float*)d_in[8];
    const float* sa_wk = (const float*)d_in[9];  const float* sa_bk = (const float*)d_in[10];
    const float* sa_wv = (const float*)d_in[11]; const float* sa_bv = (const float*)d_in[12];
    const float* sa_wo = (const float*)d_in[13]; const float* sa_bo = (const float*)d_in[14];
    const float* ca_wq = (const float*)d_in[15]; const float* ca_bq = (const float*)d_in[16];
    const float* ca_wk = (const float*)d_in[17]; const float* ca_bk = (const float*)d_in[18];
    const float* ca_wv = (const float*)d_in[19]; const float* ca_bv = (const float*)d_in[20];
    const float* ca_wo = (const float*)d_in[21]; const float* ca_bo = (const float*)d_in[22];
    const float* ff_w1 = (const float*)d_in[23]; const float* ff_b1 = (const float*)d_in[24];
    const float* ff_w2 = (const float*)d_in[25]; const float* ff_b2 = (const float*)d_in[26];
    const float* ln1g = (const float*)d_in[27]; const float* ln1b = (const float*)d_in[28];
    const float* ln2g = (const float*)d_in[29]; const float* ln2b = (const float*)d_in[30];
    const float* ln3g = (const float*)d_in[31]; const float* ln3b = (const float*)d_in[32];

    float* ws = (float*)d_ws;
    float* x    = ws;                         // 460800 f
    float* hlat = ws + 460800;                // 512 f
    u16* xb   = (u16*)(ws + 461312);          // MPAD*128 us = 237568 f
    u16* encb = (u16*)(ws + 698880);          // 237568 f
    u16* ob   = (u16*)(ws + 936448);          // 237568 f
    u16* hb   = (u16*)(ws + 1174016);         // MPAD*512 us = 950272 f
    u16* Qb   = (u16*)(ws + 2124288);         // 230400 f
    u16* Kb   = (u16*)(ws + 2354688);         // 230400 f
    u16* Vt   = (u16*)(ws + 2585088);         // 16*16*1824 us = 233472 f
    u16* wt_saq = (u16*)(ws + 2818560);       // 8 square mats, 49152 f each
    u16* wt_sak = wt_saq + 6 * 16384;
    u16* wt_sav = wt_sak + 6 * 16384;
    u16* wt_sao = wt_sav + 6 * 16384;
    u16* wt_caq = wt_sao + 6 * 16384;
    u16* wt_cak = wt_caq + 6 * 16384;
    u16* wt_cav = wt_cak + 6 * 16384;
    u16* wt_cao = wt_cav + 6 * 16384;
    u16* wt1  = (u16*)(ws + 3211776);         // [6][512][128] us = 196608 f
    u16* wt2  = (u16*)(ws + 3408384);         // [6][128][512] us = 196608 f

    // one-time per call: weight conversion + V pad zero
    wconv8_kernel<<<dim3(384, 1, 8), dim3(256), 0, stream>>>(
        sa_wq, sa_wk, sa_wv, sa_wo, ca_wq, ca_wk, ca_wv, ca_wo,
        wt_saq, wt_sak, wt_sav, wt_sao, wt_caq, wt_cak, wt_cav, wt_cao);
    wconvg_kernel<<<dim3(1536), dim3(256), 0, stream>>>(ff_w1, wt1, 7, 9);
    wconvg_kernel<<<dim3(1536), dim3(256), 0, stream>>>(ff_w2, wt2, 9, 7);
    zvt_kernel<<<dim3(32), dim3(256), 0, stream>>>(Vt);

    lat_h_kernel<<<dim3(2), dim3(256), 0, stream>>>(latent, lp_w1, lp_b1, hlat);
    dec_kernel<<<dim3(900), dim3(256), 0, stream>>>(hlat, lp_w2, lp_b2, x, xb, encb);

    const dim3 thr(256);
    const dim3 gQKV(57, 1, 3), gF(57, 16), gFF1(57, 4);

    for (int i = 0; i < Ln; ++i) {
        const size_t wOff = (size_t)i * 16384;
        const size_t bOff = (size_t)i * 128;
        const size_t fOff = (size_t)i * 65536;
        const size_t f1b  = (size_t)i * 512;

        // ---- self attention ----
        mm_qkv_kernel<<<gQKV, thr, 0, stream>>>(
            xb, xb, wt_saq + wOff, wt_sak + wOff, wt_sav + wOff,
            sa_bq + bOff, sa_bk + bOff, sa_bv + bOff, Qb, Kb, Vt);
        vmean_kernel<<<dim3(256), dim3(64), 0, stream>>>(Vt, ob);
        flash_mfma<1><<<gF, dim3(64), 0, stream>>>(Qb, Kb, Vt, ob);
        mm_oln_kernel<8><<<dim3(57), thr, 0, stream>>>(
            ob, wt_sao + wOff, sa_bo + bOff, x, ln1g + bOff, ln1b + bOff, x, xb);

        // ---- cross attention (K/V from enc) ----
        mm_qkv_kernel<<<gQKV, thr, 0, stream>>>(
            xb, encb, wt_caq + wOff, wt_cak + wOff, wt_cav + wOff,
            ca_bq + bOff, ca_bk + bOff, ca_bv + bOff, Qb, Kb, Vt);
        flash_mfma<0><<<gF, dim3(64), 0, stream>>>(Qb, Kb, Vt, ob);
        mm_oln_kernel<8><<<dim3(57), thr, 0, stream>>>(
            ob, wt_cao + wOff, ca_bo + bOff, x, ln2g + bOff, ln2b + bOff, x, xb);

        // ---- ffn ----
        mm_ff1_kernel<<<gFF1, thr, 0, stream>>>(xb, wt1 + fOff, ff_b1 + f1b, hb);
        mm_oln_kernel<32><<<dim3(57), thr, 0, stream>>>(
            hb, wt2 + fOff, ff_b2 + bOff, x, ln3g + bOff, ln3b + bOff, x, xb);
    }

    out_kernel<<<dim3(225), dim3(256), 0, stream>>>(x, out_w, out_b, (float*)d_out);
}

// Round 4
// 715.443 us; speedup vs baseline: 3.1114x; 1.3713x over previous
//
#include <hip/hip_runtime.h>
#include <hip/hip_bf16.h>
#include <math.h>

// Problem constants
#define Bn   2
#define Sn   1800
#define Dn   128
#define Hn   8
#define DKn  16
#define DFFn 512
#define Ln   6
#define Vn   16
#define LATn 1024
#define BSn  3600        // B*S
#define SDn  230400      // S*D
#define NQT  57          // ceil(1800/32)
#define VTJ  1824        // padded j-dim of transposed V
#define MPAD 3712        // padded row count for bf16 activation buffers

typedef __attribute__((ext_vector_type(8))) short short8;   // 8 bf16 = 4 VGPR
typedef __attribute__((ext_vector_type(16))) float f32x16;
typedef unsigned int u32;
typedef unsigned short u16;

// MFMA 32x32x16 C/D layout: row = (reg&3) + 8*(reg>>2) + 4*hi, col = lane&31
#define ROWMAP(r, hi) (((r) & 3) + 8 * ((r) >> 2) + 4 * (hi))
// V-column permutation so PV's B-fragment needs no cross-lane exchange:
// slot pos holds actual j = g(pos); g is an involution (bit2 <-> bit3)
#define GPERM(sl) (((sl) & 3) + (((sl) & 4) << 1) + (((sl) & 8) >> 1) + ((sl) & 16))

__device__ inline u32 cvtpk_bf16(float a, float b) {
    u32 r;
    asm("v_cvt_pk_bf16_f32 %0, %1, %2" : "=v"(r) : "v"(a), "v"(b));
    return r;
}

__device__ inline u16 f2bf(float f) {
    union { float f; u32 u; } x; x.f = f;
    u32 r = (x.u + 0x7FFFu + ((x.u >> 16) & 1u)) >> 16;
    return (u16)r;
}

__device__ inline float bf2f(u16 v) {
    union { u32 u; float f; } x; x.u = ((u32)v) << 16;
    return x.f;
}

// ---------------------------------------------------------------------------
// Weight conversion: 8 square mats [6][128][128] fp32 -> bf16 transposed
// ---------------------------------------------------------------------------
__global__ __launch_bounds__(256) void wconv8_kernel(
    const float* __restrict__ s0, const float* __restrict__ s1,
    const float* __restrict__ s2, const float* __restrict__ s3,
    const float* __restrict__ s4, const float* __restrict__ s5,
    const float* __restrict__ s6, const float* __restrict__ s7,
    u16* __restrict__ d0, u16* __restrict__ d1, u16* __restrict__ d2,
    u16* __restrict__ d3, u16* __restrict__ d4, u16* __restrict__ d5,
    u16* __restrict__ d6, u16* __restrict__ d7)
{
    const int z = blockIdx.z;
    const float* src = (z == 0) ? s0 : (z == 1) ? s1 : (z == 2) ? s2 : (z == 3) ? s3
                     : (z == 4) ? s4 : (z == 5) ? s5 : (z == 6) ? s6 : s7;
    u16* dst = (z == 0) ? d0 : (z == 1) ? d1 : (z == 2) ? d2 : (z == 3) ? d3
             : (z == 4) ? d4 : (z == 5) ? d5 : (z == 6) ? d6 : d7;
    const int id = blockIdx.x * 256 + threadIdx.x;   // < 6*16384
    const int l = id >> 14, rem = id & 16383;
    const int n = rem >> 7, k = rem & 127;
    dst[id] = f2bf(src[l * 16384 + k * 128 + n]);
}

// generic: dst[l][n][k] = src[l][k][n], K = 1<<logK (contraction), N = 1<<logN
__global__ __launch_bounds__(256) void wconvg_kernel(
    const float* __restrict__ src, u16* __restrict__ dst, int logK, int logN)
{
    const int id = blockIdx.x * 256 + threadIdx.x;
    const int kn = 1 << (logK + logN);
    const int l = id >> (logK + logN);
    const int rem = id & (kn - 1);
    const int n = rem >> logK, k = rem & ((1 << logK) - 1);
    dst[id] = f2bf(src[(size_t)l * kn + (k << logN) + n]);
}

// zero V^T tile-56 slots (positions 1792..1823) so unwritten slots are 0
__global__ __launch_bounds__(256) void zvt_kernel(u16* __restrict__ Vt)
{
    const int id = blockIdx.x * 256 + threadIdx.x;   // < 256*32 = 8192
    const int row = id >> 5, pos = id & 31;
    Vt[(size_t)row * VTJ + 1792 + pos] = 0;
}

// ---------------------------------------------------------------------------
// h = relu(latent @ lp_w1 + lp_b1)   [2, 256]
// ---------------------------------------------------------------------------
__global__ __launch_bounds__(256) void lat_h_kernel(
    const float* __restrict__ latent, const float* __restrict__ w1,
    const float* __restrict__ b1, float* __restrict__ h)
{
    __shared__ float ls[LATn];
    const int b = blockIdx.x;
    const int t = threadIdx.x;
    for (int k = t; k < LATn; k += 256) ls[k] = latent[b * LATn + k];
    __syncthreads();
    float acc = 0.f;
    #pragma unroll 8
    for (int k = 0; k < LATn; ++k) acc = fmaf(ls[k], w1[(size_t)k * 256 + t], acc);
    h[b * 256 + t] = fmaxf(acc + b1[t], 0.f);
}

// ---------------------------------------------------------------------------
// dec = h @ lp_w2 + lp_b2 + pos_encoding ; writes fp32 x and bf16 xb, encb
// ---------------------------------------------------------------------------
__global__ __launch_bounds__(256) void dec_kernel(
    const float* __restrict__ h, const float* __restrict__ w2,
    const float* __restrict__ b2, float* __restrict__ x,
    u16* __restrict__ xb, u16* __restrict__ encb)
{
    __shared__ float hs[512];
    const int t = threadIdx.x;
    hs[t] = h[t];
    hs[256 + t] = h[256 + t];
    __syncthreads();
    const int j = blockIdx.x * 256 + t;
    float a0 = 0.f, a1 = 0.f;
    #pragma unroll 8
    for (int k = 0; k < 256; ++k) {
        float w = w2[(size_t)k * SDn + j];
        a0 = fmaf(hs[k], w, a0);
        a1 = fmaf(hs[256 + k], w, a1);
    }
    const int s = j >> 7, d = j & 127;
    const int i2 = d >> 1;
    const float freq = __expf(-(float)(2 * i2) * (9.210340371976184f / 128.f));
    const float ang = (float)s * freq;
    const float pe = (d & 1) ? cosf(ang) : sinf(ang);
    const float bias = b2[j] + pe;
    const float v0 = a0 + bias;
    const float v1 = a1 + bias;
    x[j] = v0;
    x[SDn + j] = v1;
    xb[j] = f2bf(v0);    xb[SDn + j] = f2bf(v1);
    encb[j] = f2bf(v0);  encb[SDn + j] = f2bf(v1);
}

// ---------------------------------------------------------------------------
// QKV projection, bf16 MFMA, fused bf16 re-layout epilogue.
// grid (57, 1, 3): z=0 Q (scaled 0.25), z=1 K, z=2 V (permuted transpose).
// ---------------------------------------------------------------------------
__global__ __launch_bounds__(256) void mm_qkv_kernel(
    const u16* __restrict__ Aq, const u16* __restrict__ Akv,
    const u16* __restrict__ Wq, const u16* __restrict__ Wk, const u16* __restrict__ Wv,
    const float* __restrict__ bq, const float* __restrict__ bk, const float* __restrict__ bv,
    u16* __restrict__ Qb, u16* __restrict__ Kb, u16* __restrict__ Vt)
{
    const int z = blockIdx.z;
    const u16* A = (z == 0) ? Aq : Akv;
    const u16* W = (z == 0) ? Wq : (z == 1) ? Wk : Wv;
    const float* Bi = (z == 0) ? bq : (z == 1) ? bk : bv;

    const int w = threadIdx.x >> 6;
    const int lane = threadIdx.x & 63;
    const int ql = lane & 31, hi = lane >> 5;
    const int m0 = blockIdx.x * 64 + (w & 1) * 32;
    const int nh = (w >> 1) * 64;

    f32x16 acc0 = (f32x16)0.0f, acc1 = (f32x16)0.0f;
    const size_t arow = (size_t)(m0 + ql) * 128;

    #pragma unroll
    for (int kk = 0; kk < 8; ++kk) {
        const short8 a = *(const short8*)(A + arow + kk * 16 + 8 * hi);
        const short8 b0 = *(const short8*)(W + (size_t)(nh + ql) * 128 + kk * 16 + 8 * hi);
        const short8 b1 = *(const short8*)(W + (size_t)(nh + 32 + ql) * 128 + kk * 16 + 8 * hi);
        acc0 = __builtin_amdgcn_mfma_f32_32x32x16_bf16(a, b0, acc0, 0, 0, 0);
        acc1 = __builtin_amdgcn_mfma_f32_32x32x16_bf16(a, b1, acc1, 0, 0, 0);
    }

    #pragma unroll
    for (int j = 0; j < 2; ++j) {
        const int n = nh + j * 32 + ql;
        const float bv_ = Bi[n];
        const int h = n >> 4, d = n & 15;
        #pragma unroll
        for (int r = 0; r < 16; ++r) {
            const int m = m0 + ROWMAP(r, hi);
            if (m >= BSn) continue;
            float v = (j ? acc1[r] : acc0[r]) + bv_;
            const int bq_ = (m >= Sn) ? 1 : 0;
            const int s = m - bq_ * Sn;
            const int bh = bq_ * 8 + h;
            if (z == 0) {
                Qb[((size_t)bh * Sn + s) * 16 + d] = f2bf(v * 0.25f);
            } else if (z == 1) {
                Kb[((size_t)bh * Sn + s) * 16 + d] = f2bf(v);
            } else {
                const int jt = s >> 5, sl = s & 31;
                Vt[((size_t)bh * 16 + d) * VTJ + jt * 32 + GPERM(sl)] = f2bf(v);
            }
        }
    }
}

// ---------------------------------------------------------------------------
// GEMM + bias + residual + LayerNorm fused.  A bf16 [MPAD][K], Wt bf16 [128][K].
// grid 114, block 256 (4 waves). BM=32; wave w owns n-slice [w*32, w*32+32).
// ---------------------------------------------------------------------------
template <int KS>
__global__ __launch_bounds__(256) void mm_oln_kernel(
    const u16* __restrict__ A, const u16* __restrict__ Wt,
    const float* __restrict__ Bi, const float* __restrict__ xres,
    const float* __restrict__ g, const float* __restrict__ bb,
    float* __restrict__ X, u16* __restrict__ XB)
{
    __shared__ float ls[32 * 132];
    __shared__ float mus[32], invs[32];

    const int t = threadIdx.x;
    const int w = t >> 6;
    const int lane = t & 63;
    const int ql = lane & 31, hi = lane >> 5;
    const int K = KS * 16;
    const int nh = w * 32;
    const int m0 = blockIdx.x * 32;

    f32x16 acc = (f32x16)0.0f;
    const size_t arow = (size_t)(m0 + ql) * K;

    #pragma unroll
    for (int kk = 0; kk < KS; ++kk) {
        const short8 a = *(const short8*)(A + arow + kk * 16 + 8 * hi);
        const short8 b0 = *(const short8*)(Wt + (size_t)(nh + ql) * K + kk * 16 + 8 * hi);
        acc = __builtin_amdgcn_mfma_f32_32x32x16_bf16(a, b0, acc, 0, 0, 0);
    }

    const int n = nh + ql;
    const float bv_ = Bi[n];
    #pragma unroll
    for (int r = 0; r < 16; ++r) {
        const int row = ROWMAP(r, hi);
        const int gm = m0 + row;
        float v = acc[r] + bv_;
        if (gm < BSn) v += xres[(size_t)gm * 128 + n];
        ls[row * 132 + n] = v;
    }
    __syncthreads();

    // stats: 8 threads per row, 16 cols each
    {
        const int row = t >> 3, q = t & 7;
        float s1 = 0.f, s2 = 0.f;
        const float* lr = &ls[row * 132 + q * 16];
        #pragma unroll
        for (int c = 0; c < 16; c += 4) {
            const float4 v = *(const float4*)&lr[c];
            s1 += v.x + v.y + v.z + v.w;
            s2 += v.x * v.x + v.y * v.y + v.z * v.z + v.w * v.w;
        }
        s1 += __shfl_xor(s1, 1); s2 += __shfl_xor(s2, 1);
        s1 += __shfl_xor(s1, 2); s2 += __shfl_xor(s2, 2);
        s1 += __shfl_xor(s1, 4); s2 += __shfl_xor(s2, 4);
        const float mu = s1 * (1.f / 128.f);
        const float var = s2 * (1.f / 128.f) - mu * mu;
        if (q == 0) { mus[row] = mu; invs[row] = rsqrtf(var + 1e-5f); }
    }
    __syncthreads();

    // write: 32 rows x 32 float4-groups = 1024 slots; 4 iters x 256 threads
    #pragma unroll
    for (int it = 0; it < 4; ++it) {
        const int idx = it * 256 + t;
        const int row = idx >> 5, cg = (idx & 31) * 4;
        const int gm = m0 + row;
        if (gm >= BSn) continue;
        const float4 v = *(const float4*)&ls[row * 132 + cg];
        const float mu = mus[row], inv = invs[row];
        const float4 gv = *(const float4*)&g[cg];
        const float4 bv2 = *(const float4*)&bb[cg];
        float4 y;
        y.x = (v.x - mu) * inv * gv.x + bv2.x;
        y.y = (v.y - mu) * inv * gv.y + bv2.y;
        y.z = (v.z - mu) * inv * gv.z + bv2.z;
        y.w = (v.w - mu) * inv * gv.w + bv2.w;
        *(float4*)&X[(size_t)gm * 128 + cg] = y;
        uint2 u;
        u.x = cvtpk_bf16(y.x, y.y);
        u.y = cvtpk_bf16(y.z, y.w);
        *(uint2*)&XB[(size_t)gm * 128 + cg] = u;
    }
}

// ---------------------------------------------------------------------------
// FF1: h = relu(x @ W1 + b1), bf16 out [MPAD][512].  grid (57, 4).
// ---------------------------------------------------------------------------
__global__ __launch_bounds__(256) void mm_ff1_kernel(
    const u16* __restrict__ A, const u16* __restrict__ Wt,
    const float* __restrict__ Bi, u16* __restrict__ Hb)
{
    const int t = threadIdx.x;
    const int w = t >> 6;
    const int lane = t & 63;
    const int ql = lane & 31, hi = lane >> 5;
    const int m0 = blockIdx.x * 64 + (w & 1) * 32;
    const int n0 = blockIdx.y * 128 + (w >> 1) * 64;

    f32x16 acc0 = (f32x16)0.0f, acc1 = (f32x16)0.0f;
    const size_t arow = (size_t)(m0 + ql) * 128;

    #pragma unroll
    for (int kk = 0; kk < 8; ++kk) {
        const short8 a = *(const short8*)(A + arow + kk * 16 + 8 * hi);
        const short8 b0 = *(const short8*)(Wt + (size_t)(n0 + ql) * 128 + kk * 16 + 8 * hi);
        const short8 b1 = *(const short8*)(Wt + (size_t)(n0 + 32 + ql) * 128 + kk * 16 + 8 * hi);
        acc0 = __builtin_amdgcn_mfma_f32_32x32x16_bf16(a, b0, acc0, 0, 0, 0);
        acc1 = __builtin_amdgcn_mfma_f32_32x32x16_bf16(a, b1, acc1, 0, 0, 0);
    }

    #pragma unroll
    for (int j = 0; j < 2; ++j) {
        const int n = n0 + j * 32 + ql;
        const float bv_ = Bi[n];
        #pragma unroll
        for (int r = 0; r < 16; ++r) {
            const int m = m0 + ROWMAP(r, hi);
            const float v = fmaxf((j ? acc1[r] : acc0[r]) + bv_, 0.f);
            Hb[(size_t)m * 512 + n] = f2bf(v);
        }
    }
}

// ---------------------------------------------------------------------------
// MFMA flash attention, 4-way split-KV.  Block = 256 threads (4 waves),
// grid (NQT [+1 if MASK], 16).  Wave w handles jt = jt0+w, +4, ... with
// private online-softmax state; LDS merge at the end (acc[0..7] + m + l).
// Swapped QK^T (q = lane&31); PV via permuted V^T -> no cross-lane pack.
// MASK=1: strictly-upper mask (keep j > i), -1e9, tiles jt >= qt only;
// fully-masked row 1799 written by the fused blockIdx.x==NQT branch
// (= uniform softmax -> mean of V).
// ---------------------------------------------------------------------------
template <int MASK>
__global__ __launch_bounds__(256) void flash_mfma(
    const u16* __restrict__ Qb, const u16* __restrict__ Kb,
    const u16* __restrict__ Vt, u16* __restrict__ Ob)
{
    __shared__ float mrg[4][64][10];

    const int wid = threadIdx.x >> 6;
    const int lane = threadIdx.x & 63;
    const int bh = blockIdx.y;
    const int b = bh >> 3, h = bh & 7;

    if (MASK && blockIdx.x == NQT) {
        // row 1799: uniform softmax over all 1800 -> mean of V
        const int d = threadIdx.x & 15, part = threadIdx.x >> 4;
        const u16* row = Vt + ((size_t)bh * 16 + d) * VTJ;
        float s = 0.f;
        for (int j = part; j < VTJ; j += 16) s += bf2f(row[j]);  // pad slots 0
        ((float*)mrg)[part * 16 + d] = s;
        __syncthreads();
        if (threadIdx.x < 16) {
            float tot = 0.f;
            #pragma unroll
            for (int p = 0; p < 16; ++p) tot += ((float*)mrg)[p * 16 + threadIdx.x];
            Ob[((size_t)(b * Sn + (Sn - 1))) * 128 + h * 16 + threadIdx.x] =
                f2bf(tot * (1.f / (float)Sn));
        }
        return;
    }

    const int ql = lane & 31, hi = lane >> 5;
    const int qt = blockIdx.x;
    const int qrow = qt * 32 + ql;
    const int qr = (qrow < Sn) ? qrow : (Sn - 1);
    const short8 qf = *(const short8*)(Qb + ((size_t)bh * Sn + qr) * 16 + 8 * hi);
    const u16* kbase = Kb + (size_t)bh * Sn * 16;
    const u16* vbase = Vt + ((size_t)bh * 16 + (ql & 15)) * VTJ;

    f32x16 acc = (f32x16)0.0f;
    float m = -INFINITY, lsum = 0.f;

    int jt = (MASK ? qt : 0) + wid;
    short8 kf = (short8)0, va = (short8)0, vb2 = (short8)0;
    if (jt < NQT) {
        int krow = jt * 32 + ql; if (krow >= Sn) krow = Sn - 1;
        kf  = *(const short8*)(kbase + (size_t)krow * 16 + 8 * hi);
        va  = *(const short8*)(vbase + jt * 32 + 8 * hi);
        vb2 = *(const short8*)(vbase + jt * 32 + 16 + 8 * hi);
    }

    for (; jt < NQT; jt += 4) {
        short8 kn = kf, van = va, vbn = vb2;
        if (jt + 4 < NQT) {
            int nrow = (jt + 4) * 32 + ql; if (nrow >= Sn) nrow = Sn - 1;
            kn  = *(const short8*)(kbase + (size_t)nrow * 16 + 8 * hi);
            van = *(const short8*)(vbase + (jt + 4) * 32 + 8 * hi);
            vbn = *(const short8*)(vbase + (jt + 4) * 32 + 16 + 8 * hi);
        }

        const f32x16 sc = __builtin_amdgcn_mfma_f32_32x32x16_bf16(kf, qf, (f32x16)0.0f, 0, 0, 0);

        float sv[16];
        #pragma unroll
        for (int r = 0; r < 16; ++r) sv[r] = sc[r];

        if (MASK && jt == qt) {     // only wave 0 ever hits jt == qt
            #pragma unroll
            for (int r = 0; r < 16; ++r)
                if (!(ROWMAP(r, hi) > ql)) sv[r] = -1e9f;
        }
        if (jt == NQT - 1) {
            #pragma unroll
            for (int r = 0; r < 16; ++r)
                if (1792 + ROWMAP(r, hi) >= Sn) sv[r] = -1e30f;
        }

        float tmax = sv[0];
        #pragma unroll
        for (int r = 1; r < 16; ++r) tmax = fmaxf(tmax, sv[r]);
        tmax = fmaxf(tmax, __shfl_xor(tmax, 32));
        const float mnew = fmaxf(m, tmax);
        const float corr = __expf(m - mnew);
        m = mnew;
        lsum *= corr;
        #pragma unroll
        for (int r = 0; r < 16; ++r) acc[r] *= corr;

        float p[16];
        float ps = 0.f;
        #pragma unroll
        for (int r = 0; r < 16; ++r) { p[r] = __expf(sv[r] - mnew); ps += p[r]; }
        lsum += ps;

        union { u32 u[4]; short8 s; } B0c, B1c;
        B0c.u[0] = cvtpk_bf16(p[0],  p[1]);  B0c.u[1] = cvtpk_bf16(p[2],  p[3]);
        B0c.u[2] = cvtpk_bf16(p[4],  p[5]);  B0c.u[3] = cvtpk_bf16(p[6],  p[7]);
        B1c.u[0] = cvtpk_bf16(p[8],  p[9]);  B1c.u[1] = cvtpk_bf16(p[10], p[11]);
        B1c.u[2] = cvtpk_bf16(p[12], p[13]); B1c.u[3] = cvtpk_bf16(p[14], p[15]);

        acc = __builtin_amdgcn_mfma_f32_32x32x16_bf16(va,  B0c.s, acc, 0, 0, 0);
        acc = __builtin_amdgcn_mfma_f32_32x32x16_bf16(vb2, B1c.s, acc, 0, 0, 0);

        kf = kn; va = van; vb2 = vbn;
    }

    // merge the 4 per-wave partials
    mrg[wid][lane][0] = m;
    mrg[wid][lane][1] = lsum;
    #pragma unroll
    for (int r = 0; r < 8; ++r) mrg[wid][lane][2 + r] = acc[r];
    __syncthreads();

    if (wid == 0) {
        float mstar = mrg[0][lane][0];
        #pragma unroll
        for (int w2 = 1; w2 < 4; ++w2) mstar = fmaxf(mstar, mrg[w2][lane][0]);
        float lt = 0.f;
        float accf[8] = {};
        #pragma unroll
        for (int w2 = 0; w2 < 4; ++w2) {
            const float sc2 = __expf(mrg[w2][lane][0] - mstar);
            lt += mrg[w2][lane][1] * sc2;
            #pragma unroll
            for (int r = 0; r < 8; ++r) accf[r] = fmaf(mrg[w2][lane][2 + r], sc2, accf[r]);
        }
        const float ltot = lt + __shfl_xor(lt, 32);
        const float inv = 1.f / ltot;
        if (qrow < Sn && !(MASK && qrow == Sn - 1)) {
            u16* op = Ob + ((size_t)(b * Sn + qrow)) * 128 + h * 16;
            uint2 u0, u1;
            u0.x = cvtpk_bf16(accf[0] * inv, accf[1] * inv);
            u0.y = cvtpk_bf16(accf[2] * inv, accf[3] * inv);
            u1.x = cvtpk_bf16(accf[4] * inv, accf[5] * inv);
            u1.y = cvtpk_bf16(accf[6] * inv, accf[7] * inv);
            *(uint2*)(op + 4 * hi) = u0;        // d = 4*hi .. 4*hi+3
            *(uint2*)(op + 8 + 4 * hi) = u1;    // d = 8+4*hi .. 8+4*hi+3
        }
    }
}

// ---------------------------------------------------------------------------
// logits = x @ out_w + out_b   [3600,128]@[128,16]  (fp32)
// ---------------------------------------------------------------------------
__global__ __launch_bounds__(256) void out_kernel(
    const float* __restrict__ X, const float* __restrict__ W,
    const float* __restrict__ bb, float* __restrict__ out)
{
    const int t = threadIdx.x;
    const int n = t & 15;
    const int r = blockIdx.x * 16 + (t >> 4);
    if (r >= BSn) return;
    float acc = 0.f;
    #pragma unroll 8
    for (int k = 0; k < 128; ++k)
        acc = fmaf(X[(size_t)r * 128 + k], W[k * 16 + n], acc);
    out[(size_t)r * 16 + n] = acc + bb[n];
}

// ---------------------------------------------------------------------------
extern "C" void kernel_launch(void* const* d_in, const int* in_sizes, int n_in,
                              void* d_out, int out_size, void* d_ws, size_t ws_size,
                              hipStream_t stream)
{
    const float* latent = (const float*)d_in[0];
    const float* lp_w1  = (const float*)d_in[1];
    const float* lp_b1  = (const float*)d_in[2];
    const float* lp_w2  = (const float*)d_in[3];
    const float* lp_b2  = (const float*)d_in[4];
    const float* out_w  = (const float*)d_in[5];
    const float* out_b  = (const float*)d_in[6];
    const float* sa_wq = (const float*)d_in[7];  const float* sa_bq = (const float*)d_in[8];
    const float* sa_wk = (const float*)d_in[9];  const float* sa_bk = (const float*)d_in[10];
    const float* sa_wv = (const float*)d_in[11]; const float* sa_bv = (const float*)d_in[12];
    const float* sa_wo = (const float*)d_in[13]; const float* sa_bo = (const float*)d_in[14];
    const float* ca_wq = (const float*)d_in[15]; const float* ca_bq = (const float*)d_in[16];
    const float* ca_wk = (const float*)d_in[17]; const float* ca_bk = (const float*)d_in[18];
    const float* ca_wv = (const float*)d_in[19]; const float* ca_bv = (const float*)d_in[20];
    const float* ca_wo = (const float*)d_in[21]; const float* ca_bo = (const float*)d_in[22];
    const float* ff_w1 = (const float*)d_in[23]; const float* ff_b1 = (const float*)d_in[24];
    const float* ff_w2 = (const float*)d_in[25]; const float* ff_b2 = (const float*)d_in[26];
    const float* ln1g = (const float*)d_in[27]; const float* ln1b = (const float*)d_in[28];
    const float* ln2g = (const float*)d_in[29]; const float* ln2b = (const float*)d_in[30];
    const float* ln3g = (const float*)d_in[31]; const float* ln3b = (const float*)d_in[32];

    float* ws = (float*)d_ws;
    float* x    = ws;                         // 460800 f
    float* hlat = ws + 460800;                // 512 f
    u16* xb   = (u16*)(ws + 461312);          // MPAD*128 us = 237568 f
    u16* encb = (u16*)(ws + 698880);          // 237568 f
    u16* ob   = (u16*)(ws + 936448);          // 237568 f
    u16* hb   = (u16*)(ws + 1174016);         // MPAD*512 us = 950272 f
    u16* Qb   = (u16*)(ws + 2124288);         // 230400 f
    u16* Kb   = (u16*)(ws + 2354688);         // 230400 f
    u16* Vt   = (u16*)(ws + 2585088);         // 16*16*1824 us = 233472 f
    u16* wt_saq = (u16*)(ws + 2818560);       // 8 square mats, 49152 f each
    u16* wt_sak = wt_saq + 6 * 16384;
    u16* wt_sav = wt_sak + 6 * 16384;
    u16* wt_sao = wt_sav + 6 * 16384;
    u16* wt_caq = wt_sao + 6 * 16384;
    u16* wt_cak = wt_caq + 6 * 16384;
    u16* wt_cav = wt_cak + 6 * 16384;
    u16* wt_cao = wt_cav + 6 * 16384;
    u16* wt1  = (u16*)(ws + 3211776);         // [6][512][128] us = 196608 f
    u16* wt2  = (u16*)(ws + 3408384);         // [6][128][512] us = 196608 f

    // one-time per call: weight conversion + V pad zero
    wconv8_kernel<<<dim3(384, 1, 8), dim3(256), 0, stream>>>(
        sa_wq, sa_wk, sa_wv, sa_wo, ca_wq, ca_wk, ca_wv, ca_wo,
        wt_saq, wt_sak, wt_sav, wt_sao, wt_caq, wt_cak, wt_cav, wt_cao);
    wconvg_kernel<<<dim3(1536), dim3(256), 0, stream>>>(ff_w1, wt1, 7, 9);
    wconvg_kernel<<<dim3(1536), dim3(256), 0, stream>>>(ff_w2, wt2, 9, 7);
    zvt_kernel<<<dim3(32), dim3(256), 0, stream>>>(Vt);

    lat_h_kernel<<<dim3(2), dim3(256), 0, stream>>>(latent, lp_w1, lp_b1, hlat);
    dec_kernel<<<dim3(900), dim3(256), 0, stream>>>(hlat, lp_w2, lp_b2, x, xb, encb);

    const dim3 thr(256);
    const dim3 gQKV(57, 1, 3), gFF1(57, 4);
    const dim3 gFm(NQT + 1, 16), gFc(NQT, 16);

    for (int i = 0; i < Ln; ++i) {
        const size_t wOff = (size_t)i * 16384;
        const size_t bOff = (size_t)i * 128;
        const size_t fOff = (size_t)i * 65536;
        const size_t f1b  = (size_t)i * 512;

        // ---- self attention ----
        mm_qkv_kernel<<<gQKV, thr, 0, stream>>>(
            xb, xb, wt_saq + wOff, wt_sak + wOff, wt_sav + wOff,
            sa_bq + bOff, sa_bk + bOff, sa_bv + bOff, Qb, Kb, Vt);
        flash_mfma<1><<<gFm, thr, 0, stream>>>(Qb, Kb, Vt, ob);
        mm_oln_kernel<8><<<dim3(114), thr, 0, stream>>>(
            ob, wt_sao + wOff, sa_bo + bOff, x, ln1g + bOff, ln1b + bOff, x, xb);

        // ---- cross attention (K/V from enc) ----
        mm_qkv_kernel<<<gQKV, thr, 0, stream>>>(
            xb, encb, wt_caq + wOff, wt_cak + wOff, wt_cav + wOff,
            ca_bq + bOff, ca_bk + bOff, ca_bv + bOff, Qb, Kb, Vt);
        flash_mfma<0><<<gFc, thr, 0, stream>>>(Qb, Kb, Vt, ob);
        mm_oln_kernel<8><<<dim3(114), thr, 0, stream>>>(
            ob, wt_cao + wOff, ca_bo + bOff, x, ln2g + bOff, ln2b + bOff, x, xb);

        // ---- ffn ----
        mm_ff1_kernel<<<gFF1, thr, 0, stream>>>(xb, wt1 + fOff, ff_b1 + f1b, hb);
        mm_oln_kernel<32><<<dim3(114), thr, 0, stream>>>(
            hb, wt2 + fOff, ff_b2 + bOff, x, ln3g + bOff, ln3b + bOff, x, xb);
    }

    out_kernel<<<dim3(225), dim3(256), 0, stream>>>(x, out_w, out_b, (float*)d_out);
}

// Round 5
// 616.196 us; speedup vs baseline: 3.6126x; 1.1611x over previous
//
#include <hip/hip_runtime.h>
#include <hip/hip_bf16.h>
#include <math.h>

// Problem constants
#define Bn   2
#define Sn   1800
#define Dn   128
#define Hn   8
#define DKn  16
#define DFFn 512
#define Ln   6
#define Vn   16
#define LATn 1024
#define BSn  3600        // B*S
#define SDn  230400      // S*D
#define NQT  57          // ceil(1800/32)
#define VTJ  1824        // padded j-dim of transposed V
#define MPAD 3712        // padded row count for bf16 activation buffers

typedef __attribute__((ext_vector_type(8))) short short8;   // 8 bf16 = 4 VGPR
typedef __attribute__((ext_vector_type(16))) float f32x16;
typedef unsigned int u32;
typedef unsigned short u16;

// MFMA 32x32x16 C/D layout: row = (reg&3) + 8*(reg>>2) + 4*hi, col = lane&31
#define ROWMAP(r, hi) (((r) & 3) + 8 * ((r) >> 2) + 4 * (hi))
// V-column permutation so PV's B-fragment needs no cross-lane exchange:
// slot pos holds actual j = g(pos); g is an involution (bit2 <-> bit3)
#define GPERM(sl) (((sl) & 3) + (((sl) & 4) << 1) + (((sl) & 8) >> 1) + ((sl) & 16))

__device__ inline u32 cvtpk_bf16(float a, float b) {
    u32 r;
    asm("v_cvt_pk_bf16_f32 %0, %1, %2" : "=v"(r) : "v"(a), "v"(b));
    return r;
}

__device__ inline u16 f2bf(float f) {
    union { float f; u32 u; } x; x.f = f;
    u32 r = (x.u + 0x7FFFu + ((x.u >> 16) & 1u)) >> 16;
    return (u16)r;
}

__device__ inline float bf2f(u16 v) {
    union { u32 u; float f; } x; x.u = ((u32)v) << 16;
    return x.f;
}

// ---------------------------------------------------------------------------
// Weight conversion: 8 square mats [6][128][128] fp32 -> bf16 transposed
// ---------------------------------------------------------------------------
__global__ __launch_bounds__(256) void wconv8_kernel(
    const float* __restrict__ s0, const float* __restrict__ s1,
    const float* __restrict__ s2, const float* __restrict__ s3,
    const float* __restrict__ s4, const float* __restrict__ s5,
    const float* __restrict__ s6, const float* __restrict__ s7,
    u16* __restrict__ d0, u16* __restrict__ d1, u16* __restrict__ d2,
    u16* __restrict__ d3, u16* __restrict__ d4, u16* __restrict__ d5,
    u16* __restrict__ d6, u16* __restrict__ d7)
{
    const int z = blockIdx.z;
    const float* src = (z == 0) ? s0 : (z == 1) ? s1 : (z == 2) ? s2 : (z == 3) ? s3
                     : (z == 4) ? s4 : (z == 5) ? s5 : (z == 6) ? s6 : s7;
    u16* dst = (z == 0) ? d0 : (z == 1) ? d1 : (z == 2) ? d2 : (z == 3) ? d3
             : (z == 4) ? d4 : (z == 5) ? d5 : (z == 6) ? d6 : d7;
    const int id = blockIdx.x * 256 + threadIdx.x;   // < 6*16384
    const int l = id >> 14, rem = id & 16383;
    const int n = rem >> 7, k = rem & 127;
    dst[id] = f2bf(src[l * 16384 + k * 128 + n]);
}

// generic: dst[l][n][k] = src[l][k][n], K = 1<<logK (contraction), N = 1<<logN
__global__ __launch_bounds__(256) void wconvg_kernel(
    const float* __restrict__ src, u16* __restrict__ dst, int logK, int logN)
{
    const int id = blockIdx.x * 256 + threadIdx.x;
    const int kn = 1 << (logK + logN);
    const int l = id >> (logK + logN);
    const int rem = id & (kn - 1);
    const int n = rem >> logK, k = rem & ((1 << logK) - 1);
    dst[id] = f2bf(src[(size_t)l * kn + (k << logN) + n]);
}

// zero V^T tile-56 slots (positions 1792..1823) so unwritten slots are 0
__global__ __launch_bounds__(256) void zvt_kernel(u16* __restrict__ Vt)
{
    const int id = blockIdx.x * 256 + threadIdx.x;   // < 256*32 = 8192
    const int row = id >> 5, pos = id & 31;
    Vt[(size_t)row * VTJ + 1792 + pos] = 0;
}

// ---------------------------------------------------------------------------
// h = relu(latent @ lp_w1 + lp_b1)   [2, 256]
// ---------------------------------------------------------------------------
__global__ __launch_bounds__(256) void lat_h_kernel(
    const float* __restrict__ latent, const float* __restrict__ w1,
    const float* __restrict__ b1, float* __restrict__ h)
{
    __shared__ float ls[LATn];
    const int b = blockIdx.x;
    const int t = threadIdx.x;
    for (int k = t; k < LATn; k += 256) ls[k] = latent[b * LATn + k];
    __syncthreads();
    float acc = 0.f;
    #pragma unroll 8
    for (int k = 0; k < LATn; ++k) acc = fmaf(ls[k], w1[(size_t)k * 256 + t], acc);
    h[b * 256 + t] = fmaxf(acc + b1[t], 0.f);
}

// ---------------------------------------------------------------------------
// dec = h @ lp_w2 + lp_b2 + pos_encoding ; writes fp32 x and bf16 xb, encb
// ---------------------------------------------------------------------------
__global__ __launch_bounds__(256) void dec_kernel(
    const float* __restrict__ h, const float* __restrict__ w2,
    const float* __restrict__ b2, float* __restrict__ x,
    u16* __restrict__ xb, u16* __restrict__ encb)
{
    __shared__ float hs[512];
    const int t = threadIdx.x;
    hs[t] = h[t];
    hs[256 + t] = h[256 + t];
    __syncthreads();
    const int j = blockIdx.x * 256 + t;
    float a0 = 0.f, a1 = 0.f;
    #pragma unroll 8
    for (int k = 0; k < 256; ++k) {
        float w = w2[(size_t)k * SDn + j];
        a0 = fmaf(hs[k], w, a0);
        a1 = fmaf(hs[256 + k], w, a1);
    }
    const int s = j >> 7, d = j & 127;
    const int i2 = d >> 1;
    const float freq = __expf(-(float)(2 * i2) * (9.210340371976184f / 128.f));
    const float ang = (float)s * freq;
    const float pe = (d & 1) ? cosf(ang) : sinf(ang);
    const float bias = b2[j] + pe;
    const float v0 = a0 + bias;
    const float v1 = a1 + bias;
    x[j] = v0;
    x[SDn + j] = v1;
    xb[j] = f2bf(v0);    xb[SDn + j] = f2bf(v1);
    encb[j] = f2bf(v0);  encb[SDn + j] = f2bf(v1);
}

// ---------------------------------------------------------------------------
// QKV projection from a global bf16 activation (layer-0 self-attn only).
// grid (57, 1, 3): z=0 Q (scaled 0.25), z=1 K, z=2 V (permuted transpose).
// ---------------------------------------------------------------------------
__global__ __launch_bounds__(256) void mm_qkv_kernel(
    const u16* __restrict__ Aq, const u16* __restrict__ Akv,
    const u16* __restrict__ Wq, const u16* __restrict__ Wk, const u16* __restrict__ Wv,
    const float* __restrict__ bq, const float* __restrict__ bk, const float* __restrict__ bv,
    u16* __restrict__ Qb, u16* __restrict__ Kb, u16* __restrict__ Vt)
{
    const int z = blockIdx.z;
    const u16* A = (z == 0) ? Aq : Akv;
    const u16* W = (z == 0) ? Wq : (z == 1) ? Wk : Wv;
    const float* Bi = (z == 0) ? bq : (z == 1) ? bk : bv;

    const int w = threadIdx.x >> 6;
    const int lane = threadIdx.x & 63;
    const int ql = lane & 31, hi = lane >> 5;
    const int m0 = blockIdx.x * 64 + (w & 1) * 32;
    const int nh = (w >> 1) * 64;

    f32x16 acc0 = (f32x16)0.0f, acc1 = (f32x16)0.0f;
    const size_t arow = (size_t)(m0 + ql) * 128;

    #pragma unroll
    for (int kk = 0; kk < 8; ++kk) {
        const short8 a = *(const short8*)(A + arow + kk * 16 + 8 * hi);
        const short8 b0 = *(const short8*)(W + (size_t)(nh + ql) * 128 + kk * 16 + 8 * hi);
        const short8 b1 = *(const short8*)(W + (size_t)(nh + 32 + ql) * 128 + kk * 16 + 8 * hi);
        acc0 = __builtin_amdgcn_mfma_f32_32x32x16_bf16(a, b0, acc0, 0, 0, 0);
        acc1 = __builtin_amdgcn_mfma_f32_32x32x16_bf16(a, b1, acc1, 0, 0, 0);
    }

    #pragma unroll
    for (int j = 0; j < 2; ++j) {
        const int n = nh + j * 32 + ql;
        const float bv_ = Bi[n];
        const int h = n >> 4, d = n & 15;
        #pragma unroll
        for (int r = 0; r < 16; ++r) {
            const int m = m0 + ROWMAP(r, hi);
            if (m >= BSn) continue;
            float v = (j ? acc1[r] : acc0[r]) + bv_;
            const int bq_ = (m >= Sn) ? 1 : 0;
            const int s = m - bq_ * Sn;
            const int bh = bq_ * 8 + h;
            if (z == 0) {
                Qb[((size_t)bh * Sn + s) * 16 + d] = f2bf(v * 0.25f);
            } else if (z == 1) {
                Kb[((size_t)bh * Sn + s) * 16 + d] = f2bf(v);
            } else {
                const int jt = s >> 5, sl = s & 31;
                Vt[((size_t)bh * 16 + d) * VTJ + jt * 32 + GPERM(sl)] = f2bf(v);
            }
        }
    }
}

// ---------------------------------------------------------------------------
// LN stats helper macro body (256 threads, 32 rows x 128 cols in ls)
// ---------------------------------------------------------------------------
__device__ inline void ln_stats(const float* ls, float* mus, float* invs, int t)
{
    const int row = t >> 3, q = t & 7;
    float s1 = 0.f, s2 = 0.f;
    const float* lr = &ls[row * 132 + q * 16];
    #pragma unroll
    for (int c = 0; c < 16; c += 4) {
        const float4 v = *(const float4*)&lr[c];
        s1 += v.x + v.y + v.z + v.w;
        s2 += v.x * v.x + v.y * v.y + v.z * v.z + v.w * v.w;
    }
    s1 += __shfl_xor(s1, 1); s2 += __shfl_xor(s2, 1);
    s1 += __shfl_xor(s1, 2); s2 += __shfl_xor(s2, 2);
    s1 += __shfl_xor(s1, 4); s2 += __shfl_xor(s2, 4);
    const float mu = s1 * (1.f / 128.f);
    const float var = s2 * (1.f / 128.f) - mu * mu;
    if (q == 0) { mus[row] = mu; invs[row] = rsqrtf(var + 1e-5f); }
}

// ---------------------------------------------------------------------------
// K2: O-proj(self) + residual + LN1 -> x (fp32) & LDS y (bf16);
// then cross-attn QKV: Q = y@Wq, K/V = encb@Wk/Wv -> Qb, Kb, Vt.
// grid 113, block 256 (4 waves, BM=32).
// ---------------------------------------------------------------------------
__global__ __launch_bounds__(256) void fuse_oln_qkv_kernel(
    const u16* __restrict__ A, const u16* __restrict__ Wo,
    const float* __restrict__ bo,
    const float* __restrict__ g, const float* __restrict__ bb,
    float* __restrict__ X, const u16* __restrict__ Enc,
    const u16* __restrict__ Wq, const u16* __restrict__ Wk, const u16* __restrict__ Wv,
    const float* __restrict__ bq, const float* __restrict__ bk, const float* __restrict__ bv,
    u16* __restrict__ Qb, u16* __restrict__ Kb, u16* __restrict__ Vt)
{
    __shared__ float ls[32 * 132];
    __shared__ float mus[32], invs[32];
    __shared__ alignas(16) u16 ybuf[32][136];   // stride 136: 68 words % 32 == 4 -> conflict-free b128

    const int t = threadIdx.x;
    const int w = t >> 6, lane = t & 63;
    const int ql = lane & 31, hi = lane >> 5;
    const int m0 = blockIdx.x * 32;

    // Phase A: a@Wo (wave w -> cols [32w,32w+32)) + bias + residual -> ls
    {
        f32x16 acc = (f32x16)0.0f;
        const size_t arow = (size_t)(m0 + ql) * 128;
        const int nh = w * 32;
        #pragma unroll
        for (int kk = 0; kk < 8; ++kk) {
            const short8 a = *(const short8*)(A + arow + kk * 16 + 8 * hi);
            const short8 b0 = *(const short8*)(Wo + (size_t)(nh + ql) * 128 + kk * 16 + 8 * hi);
            acc = __builtin_amdgcn_mfma_f32_32x32x16_bf16(a, b0, acc, 0, 0, 0);
        }
        const int n = nh + ql;
        const float bv_ = bo[n];
        #pragma unroll
        for (int r = 0; r < 16; ++r) {
            const int row = ROWMAP(r, hi);
            const int gm = m0 + row;
            float v = acc[r] + bv_;
            if (gm < BSn) v += X[(size_t)gm * 128 + n];
            ls[row * 132 + n] = v;
        }
    }
    __syncthreads();
    ln_stats(ls, mus, invs, t);
    __syncthreads();
    // write y1 -> X fp32 + ybuf bf16
    #pragma unroll
    for (int it = 0; it < 4; ++it) {
        const int idx = it * 256 + t;
        const int row = idx >> 5, cg = (idx & 31) * 4;
        const int gm = m0 + row;
        const float4 v = *(const float4*)&ls[row * 132 + cg];
        const float mu = mus[row], inv = invs[row];
        const float4 gv = *(const float4*)&g[cg];
        const float4 bv2 = *(const float4*)&bb[cg];
        float4 y;
        y.x = (v.x - mu) * inv * gv.x + bv2.x;
        y.y = (v.y - mu) * inv * gv.y + bv2.y;
        y.z = (v.z - mu) * inv * gv.z + bv2.z;
        y.w = (v.w - mu) * inv * gv.w + bv2.w;
        if (gm < BSn) *(float4*)&X[(size_t)gm * 128 + cg] = y;
        uint2 u;
        u.x = cvtpk_bf16(y.x, y.y);
        u.y = cvtpk_bf16(y.z, y.w);
        *(uint2*)&ybuf[row][cg] = u;
    }
    __syncthreads();

    // Phase B: QKV for cross-attn. Wave w owns n-slice [32w, 32w+32) of each.
    #pragma unroll
    for (int z = 0; z < 3; ++z) {
        const u16* W = (z == 0) ? Wq : (z == 1) ? Wk : Wv;
        const float* Bi = (z == 0) ? bq : (z == 1) ? bk : bv;
        f32x16 acc = (f32x16)0.0f;
        const int nh = w * 32;
        #pragma unroll
        for (int kk = 0; kk < 8; ++kk) {
            short8 a;
            if (z == 0) a = *(const short8*)&ybuf[ql][kk * 16 + 8 * hi];
            else        a = *(const short8*)(Enc + (size_t)(m0 + ql) * 128 + kk * 16 + 8 * hi);
            const short8 b0 = *(const short8*)(W + (size_t)(nh + ql) * 128 + kk * 16 + 8 * hi);
            acc = __builtin_amdgcn_mfma_f32_32x32x16_bf16(a, b0, acc, 0, 0, 0);
        }
        const int n = nh + ql;
        const float bv_ = Bi[n];
        const int h = n >> 4, d = n & 15;
        #pragma unroll
        for (int r = 0; r < 16; ++r) {
            const int m = m0 + ROWMAP(r, hi);
            if (m >= BSn) continue;
            float v = acc[r] + bv_;
            const int bq_ = (m >= Sn) ? 1 : 0;
            const int s = m - bq_ * Sn;
            const int bh = bq_ * 8 + h;
            if (z == 0)      Qb[((size_t)bh * Sn + s) * 16 + d] = f2bf(v * 0.25f);
            else if (z == 1) Kb[((size_t)bh * Sn + s) * 16 + d] = f2bf(v);
            else             Vt[((size_t)bh * 16 + d) * VTJ + (s >> 5) * 32 + GPERM(s & 31)] = f2bf(v);
        }
    }
}

// ---------------------------------------------------------------------------
// K4: O-proj(cross) + residual + LN2 (LDS only) + FF1 (h in LDS) + FF2 +
// residual + LN3 -> x; then (if WITH_QKV) next layer's self-attn QKV.
// grid 113, block 256.
// ---------------------------------------------------------------------------
template <int WITH_QKV>
__global__ __launch_bounds__(256) void fuse_ffn_kernel(
    const u16* __restrict__ A, const u16* __restrict__ Wo,
    const float* __restrict__ bo,
    const float* __restrict__ g2, const float* __restrict__ b2ln,
    const u16* __restrict__ W1, const float* __restrict__ b1,
    const u16* __restrict__ W2, const float* __restrict__ b2f,
    const float* __restrict__ g3, const float* __restrict__ b3ln,
    float* __restrict__ X,
    const u16* __restrict__ Wq, const u16* __restrict__ Wk, const u16* __restrict__ Wv,
    const float* __restrict__ bq, const float* __restrict__ bk, const float* __restrict__ bv,
    u16* __restrict__ Qb, u16* __restrict__ Kb, u16* __restrict__ Vt)
{
    __shared__ float ls[32 * 132];
    __shared__ float mus[32], invs[32];
    __shared__ alignas(16) u16 ybuf[32][136];
    __shared__ alignas(16) u16 hbuf[32][536];   // 536: 268 words % 32 == 12 -> conflict-free b128

    const int t = threadIdx.x;
    const int w = t >> 6, lane = t & 63;
    const int ql = lane & 31, hi = lane >> 5;
    const int m0 = blockIdx.x * 32;

    // Phase A: a@Wo + bias + residual -> ls
    {
        f32x16 acc = (f32x16)0.0f;
        const size_t arow = (size_t)(m0 + ql) * 128;
        const int nh = w * 32;
        #pragma unroll
        for (int kk = 0; kk < 8; ++kk) {
            const short8 a = *(const short8*)(A + arow + kk * 16 + 8 * hi);
            const short8 b0 = *(const short8*)(Wo + (size_t)(nh + ql) * 128 + kk * 16 + 8 * hi);
            acc = __builtin_amdgcn_mfma_f32_32x32x16_bf16(a, b0, acc, 0, 0, 0);
        }
        const int n = nh + ql;
        const float bv_ = bo[n];
        #pragma unroll
        for (int r = 0; r < 16; ++r) {
            const int row = ROWMAP(r, hi);
            const int gm = m0 + row;
            float v = acc[r] + bv_;
            if (gm < BSn) v += X[(size_t)gm * 128 + n];
            ls[row * 132 + n] = v;
        }
    }
    __syncthreads();
    ln_stats(ls, mus, invs, t);
    __syncthreads();
    // y2 = LN2 -> ls (fp32, residual for LN3) + ybuf (bf16, FF1 input); no global write
    #pragma unroll
    for (int it = 0; it < 4; ++it) {
        const int idx = it * 256 + t;
        const int row = idx >> 5, cg = (idx & 31) * 4;
        const float4 v = *(const float4*)&ls[row * 132 + cg];
        const float mu = mus[row], inv = invs[row];
        const float4 gv = *(const float4*)&g2[cg];
        const float4 bv2 = *(const float4*)&b2ln[cg];
        float4 y;
        y.x = (v.x - mu) * inv * gv.x + bv2.x;
        y.y = (v.y - mu) * inv * gv.y + bv2.y;
        y.z = (v.z - mu) * inv * gv.z + bv2.z;
        y.w = (v.w - mu) * inv * gv.w + bv2.w;
        *(float4*)&ls[row * 132 + cg] = y;
        uint2 u;
        u.x = cvtpk_bf16(y.x, y.y);
        u.y = cvtpk_bf16(y.z, y.w);
        *(uint2*)&ybuf[row][cg] = u;
    }
    __syncthreads();

    // Phase B: FF1. Wave w -> h cols [128w, 128w+128), 4 n-tiles.
    #pragma unroll
    for (int nt = 0; nt < 4; ++nt) {
        const int n0 = w * 128 + nt * 32;
        f32x16 acc = (f32x16)0.0f;
        #pragma unroll
        for (int kk = 0; kk < 8; ++kk) {
            const short8 a = *(const short8*)&ybuf[ql][kk * 16 + 8 * hi];
            const short8 b0 = *(const short8*)(W1 + (size_t)(n0 + ql) * 128 + kk * 16 + 8 * hi);
            acc = __builtin_amdgcn_mfma_f32_32x32x16_bf16(a, b0, acc, 0, 0, 0);
        }
        const int n = n0 + ql;
        const float bv_ = b1[n];
        #pragma unroll
        for (int r = 0; r < 16; ++r) {
            const int row = ROWMAP(r, hi);
            hbuf[row][n] = f2bf(fmaxf(acc[r] + bv_, 0.f));
        }
    }
    __syncthreads();

    // Phase C: FF2 (K=512) + bias + y2 residual -> ls
    {
        f32x16 acc = (f32x16)0.0f;
        const int nh = w * 32;
        #pragma unroll
        for (int kk = 0; kk < 32; ++kk) {
            const short8 a = *(const short8*)&hbuf[ql][kk * 16 + 8 * hi];
            const short8 b0 = *(const short8*)(W2 + (size_t)(nh + ql) * 512 + kk * 16 + 8 * hi);
            acc = __builtin_amdgcn_mfma_f32_32x32x16_bf16(a, b0, acc, 0, 0, 0);
        }
        const int n = nh + ql;
        const float bv_ = b2f[n];
        #pragma unroll
        for (int r = 0; r < 16; ++r) {
            const int row = ROWMAP(r, hi);
            ls[row * 132 + n] = acc[r] + bv_ + ls[row * 132 + n];
        }
    }
    __syncthreads();
    ln_stats(ls, mus, invs, t);
    __syncthreads();
    // y3 = LN3 -> X fp32 + ybuf bf16
    #pragma unroll
    for (int it = 0; it < 4; ++it) {
        const int idx = it * 256 + t;
        const int row = idx >> 5, cg = (idx & 31) * 4;
        const int gm = m0 + row;
        const float4 v = *(const float4*)&ls[row * 132 + cg];
        const float mu = mus[row], inv = invs[row];
        const float4 gv = *(const float4*)&g3[cg];
        const float4 bv2 = *(const float4*)&b3ln[cg];
        float4 y;
        y.x = (v.x - mu) * inv * gv.x + bv2.x;
        y.y = (v.y - mu) * inv * gv.y + bv2.y;
        y.z = (v.z - mu) * inv * gv.z + bv2.z;
        y.w = (v.w - mu) * inv * gv.w + bv2.w;
        if (gm < BSn) *(float4*)&X[(size_t)gm * 128 + cg] = y;
        uint2 u;
        u.x = cvtpk_bf16(y.x, y.y);
        u.y = cvtpk_bf16(y.z, y.w);
        *(uint2*)&ybuf[row][cg] = u;
    }

    if (WITH_QKV) {
        __syncthreads();
        // Phase D: next layer's self-attn QKV, all from ybuf
        #pragma unroll
        for (int z = 0; z < 3; ++z) {
            const u16* W = (z == 0) ? Wq : (z == 1) ? Wk : Wv;
            const float* Bi = (z == 0) ? bq : (z == 1) ? bk : bv;
            f32x16 acc = (f32x16)0.0f;
            const int nh = w * 32;
            #pragma unroll
            for (int kk = 0; kk < 8; ++kk) {
                const short8 a = *(const short8*)&ybuf[ql][kk * 16 + 8 * hi];
                const short8 b0 = *(const short8*)(W + (size_t)(nh + ql) * 128 + kk * 16 + 8 * hi);
                acc = __builtin_amdgcn_mfma_f32_32x32x16_bf16(a, b0, acc, 0, 0, 0);
            }
            const int n = nh + ql;
            const float bv_ = Bi[n];
            const int h = n >> 4, d = n & 15;
            #pragma unroll
            for (int r = 0; r < 16; ++r) {
                const int m = m0 + ROWMAP(r, hi);
                if (m >= BSn) continue;
                float v = acc[r] + bv_;
                const int bq_ = (m >= Sn) ? 1 : 0;
                const int s = m - bq_ * Sn;
                const int bh = bq_ * 8 + h;
                if (z == 0)      Qb[((size_t)bh * Sn + s) * 16 + d] = f2bf(v * 0.25f);
                else if (z == 1) Kb[((size_t)bh * Sn + s) * 16 + d] = f2bf(v);
                else             Vt[((size_t)bh * 16 + d) * VTJ + (s >> 5) * 32 + GPERM(s & 31)] = f2bf(v);
            }
        }
    }
}

// ---------------------------------------------------------------------------
// MFMA flash attention, 4-way split-KV (unchanged from round 3).
// ---------------------------------------------------------------------------
template <int MASK>
__global__ __launch_bounds__(256) void flash_mfma(
    const u16* __restrict__ Qb, const u16* __restrict__ Kb,
    const u16* __restrict__ Vt, u16* __restrict__ Ob)
{
    __shared__ float mrg[4][64][10];

    const int wid = threadIdx.x >> 6;
    const int lane = threadIdx.x & 63;
    const int bh = blockIdx.y;
    const int b = bh >> 3, h = bh & 7;

    if (MASK && blockIdx.x == NQT) {
        const int d = threadIdx.x & 15, part = threadIdx.x >> 4;
        const u16* row = Vt + ((size_t)bh * 16 + d) * VTJ;
        float s = 0.f;
        for (int j = part; j < VTJ; j += 16) s += bf2f(row[j]);
        ((float*)mrg)[part * 16 + d] = s;
        __syncthreads();
        if (threadIdx.x < 16) {
            float tot = 0.f;
            #pragma unroll
            for (int p = 0; p < 16; ++p) tot += ((float*)mrg)[p * 16 + threadIdx.x];
            Ob[((size_t)(b * Sn + (Sn - 1))) * 128 + h * 16 + threadIdx.x] =
                f2bf(tot * (1.f / (float)Sn));
        }
        return;
    }

    const int ql = lane & 31, hi = lane >> 5;
    const int qt = blockIdx.x;
    const int qrow = qt * 32 + ql;
    const int qr = (qrow < Sn) ? qrow : (Sn - 1);
    const short8 qf = *(const short8*)(Qb + ((size_t)bh * Sn + qr) * 16 + 8 * hi);
    const u16* kbase = Kb + (size_t)bh * Sn * 16;
    const u16* vbase = Vt + ((size_t)bh * 16 + (ql & 15)) * VTJ;

    f32x16 acc = (f32x16)0.0f;
    float m = -INFINITY, lsum = 0.f;

    int jt = (MASK ? qt : 0) + wid;
    short8 kf = (short8)0, va = (short8)0, vb2 = (short8)0;
    if (jt < NQT) {
        int krow = jt * 32 + ql; if (krow >= Sn) krow = Sn - 1;
        kf  = *(const short8*)(kbase + (size_t)krow * 16 + 8 * hi);
        va  = *(const short8*)(vbase + jt * 32 + 8 * hi);
        vb2 = *(const short8*)(vbase + jt * 32 + 16 + 8 * hi);
    }

    for (; jt < NQT; jt += 4) {
        short8 kn = kf, van = va, vbn = vb2;
        if (jt + 4 < NQT) {
            int nrow = (jt + 4) * 32 + ql; if (nrow >= Sn) nrow = Sn - 1;
            kn  = *(const short8*)(kbase + (size_t)nrow * 16 + 8 * hi);
            van = *(const short8*)(vbase + (jt + 4) * 32 + 8 * hi);
            vbn = *(const short8*)(vbase + (jt + 4) * 32 + 16 + 8 * hi);
        }

        const f32x16 sc = __builtin_amdgcn_mfma_f32_32x32x16_bf16(kf, qf, (f32x16)0.0f, 0, 0, 0);

        float sv[16];
        #pragma unroll
        for (int r = 0; r < 16; ++r) sv[r] = sc[r];

        if (MASK && jt == qt) {
            #pragma unroll
            for (int r = 0; r < 16; ++r)
                if (!(ROWMAP(r, hi) > ql)) sv[r] = -1e9f;
        }
        if (jt == NQT - 1) {
            #pragma unroll
            for (int r = 0; r < 16; ++r)
                if (1792 + ROWMAP(r, hi) >= Sn) sv[r] = -1e30f;
        }

        float tmax = sv[0];
        #pragma unroll
        for (int r = 1; r < 16; ++r) tmax = fmaxf(tmax, sv[r]);
        tmax = fmaxf(tmax, __shfl_xor(tmax, 32));
        const float mnew = fmaxf(m, tmax);
        const float corr = __expf(m - mnew);
        m = mnew;
        lsum *= corr;
        #pragma unroll
        for (int r = 0; r < 16; ++r) acc[r] *= corr;

        float p[16];
        float ps = 0.f;
        #pragma unroll
        for (int r = 0; r < 16; ++r) { p[r] = __expf(sv[r] - mnew); ps += p[r]; }
        lsum += ps;

        union { u32 u[4]; short8 s; } B0c, B1c;
        B0c.u[0] = cvtpk_bf16(p[0],  p[1]);  B0c.u[1] = cvtpk_bf16(p[2],  p[3]);
        B0c.u[2] = cvtpk_bf16(p[4],  p[5]);  B0c.u[3] = cvtpk_bf16(p[6],  p[7]);
        B1c.u[0] = cvtpk_bf16(p[8],  p[9]);  B1c.u[1] = cvtpk_bf16(p[10], p[11]);
        B1c.u[2] = cvtpk_bf16(p[12], p[13]); B1c.u[3] = cvtpk_bf16(p[14], p[15]);

        acc = __builtin_amdgcn_mfma_f32_32x32x16_bf16(va,  B0c.s, acc, 0, 0, 0);
        acc = __builtin_amdgcn_mfma_f32_32x32x16_bf16(vb2, B1c.s, acc, 0, 0, 0);

        kf = kn; va = van; vb2 = vbn;
    }

    mrg[wid][lane][0] = m;
    mrg[wid][lane][1] = lsum;
    #pragma unroll
    for (int r = 0; r < 8; ++r) mrg[wid][lane][2 + r] = acc[r];
    __syncthreads();

    if (wid == 0) {
        float mstar = mrg[0][lane][0];
        #pragma unroll
        for (int w2 = 1; w2 < 4; ++w2) mstar = fmaxf(mstar, mrg[w2][lane][0]);
        float lt = 0.f;
        float accf[8] = {};
        #pragma unroll
        for (int w2 = 0; w2 < 4; ++w2) {
            const float sc2 = __expf(mrg[w2][lane][0] - mstar);
            lt += mrg[w2][lane][1] * sc2;
            #pragma unroll
            for (int r = 0; r < 8; ++r) accf[r] = fmaf(mrg[w2][lane][2 + r], sc2, accf[r]);
        }
        const float ltot = lt + __shfl_xor(lt, 32);
        const float inv = 1.f / ltot;
        if (qrow < Sn && !(MASK && qrow == Sn - 1)) {
            u16* op = Ob + ((size_t)(b * Sn + qrow)) * 128 + h * 16;
            uint2 u0, u1;
            u0.x = cvtpk_bf16(accf[0] * inv, accf[1] * inv);
            u0.y = cvtpk_bf16(accf[2] * inv, accf[3] * inv);
            u1.x = cvtpk_bf16(accf[4] * inv, accf[5] * inv);
            u1.y = cvtpk_bf16(accf[6] * inv, accf[7] * inv);
            *(uint2*)(op + 4 * hi) = u0;
            *(uint2*)(op + 8 + 4 * hi) = u1;
        }
    }
}

// ---------------------------------------------------------------------------
// logits = x @ out_w + out_b   [3600,128]@[128,16]  (fp32)
// ---------------------------------------------------------------------------
__global__ __launch_bounds__(256) void out_kernel(
    const float* __restrict__ X, const float* __restrict__ W,
    const float* __restrict__ bb, float* __restrict__ out)
{
    const int t = threadIdx.x;
    const int n = t & 15;
    const int r = blockIdx.x * 16 + (t >> 4);
    if (r >= BSn) return;
    float acc = 0.f;
    #pragma unroll 8
    for (int k = 0; k < 128; ++k)
        acc = fmaf(X[(size_t)r * 128 + k], W[k * 16 + n], acc);
    out[(size_t)r * 16 + n] = acc + bb[n];
}

// ---------------------------------------------------------------------------
extern "C" void kernel_launch(void* const* d_in, const int* in_sizes, int n_in,
                              void* d_out, int out_size, void* d_ws, size_t ws_size,
                              hipStream_t stream)
{
    const float* latent = (const float*)d_in[0];
    const float* lp_w1  = (const float*)d_in[1];
    const float* lp_b1  = (const float*)d_in[2];
    const float* lp_w2  = (const float*)d_in[3];
    const float* lp_b2  = (const float*)d_in[4];
    const float* out_w  = (const float*)d_in[5];
    const float* out_b  = (const float*)d_in[6];
    const float* sa_wq = (const float*)d_in[7];  const float* sa_bq = (const float*)d_in[8];
    const float* sa_wk = (const float*)d_in[9];  const float* sa_bk = (const float*)d_in[10];
    const float* sa_wv = (const float*)d_in[11]; const float* sa_bv = (const float*)d_in[12];
    const float* sa_wo = (const float*)d_in[13]; const float* sa_bo = (const float*)d_in[14];
    const float* ca_wq = (const float*)d_in[15]; const float* ca_bq = (const float*)d_in[16];
    const float* ca_wk = (const float*)d_in[17]; const float* ca_bk = (const float*)d_in[18];
    const float* ca_wv = (const float*)d_in[19]; const float* ca_bv = (const float*)d_in[20];
    const float* ca_wo = (const float*)d_in[21]; const float* ca_bo = (const float*)d_in[22];
    const float* ff_w1 = (const float*)d_in[23]; const float* ff_b1 = (const float*)d_in[24];
    const float* ff_w2 = (const float*)d_in[25]; const float* ff_b2 = (const float*)d_in[26];
    const float* ln1g = (const float*)d_in[27]; const float* ln1b = (const float*)d_in[28];
    const float* ln2g = (const float*)d_in[29]; const float* ln2b = (const float*)d_in[30];
    const float* ln3g = (const float*)d_in[31]; const float* ln3b = (const float*)d_in[32];

    float* ws = (float*)d_ws;
    float* x    = ws;                         // 460800 f
    float* hlat = ws + 460800;                // 512 f
    u16* xb   = (u16*)(ws + 461312);          // MPAD*128 us = 237568 f (layer-0 only)
    u16* encb = (u16*)(ws + 698880);          // 237568 f
    u16* ob   = (u16*)(ws + 936448);          // 237568 f
    u16* Qb   = (u16*)(ws + 2124288);         // 230400 f
    u16* Kb   = (u16*)(ws + 2354688);         // 230400 f
    u16* Vt   = (u16*)(ws + 2585088);         // 16*16*1824 us = 233472 f
    u16* wt_saq = (u16*)(ws + 2818560);       // 8 square mats, 49152 f each
    u16* wt_sak = wt_saq + 6 * 16384;
    u16* wt_sav = wt_sak + 6 * 16384;
    u16* wt_sao = wt_sav + 6 * 16384;
    u16* wt_caq = wt_sao + 6 * 16384;
    u16* wt_cak = wt_caq + 6 * 16384;
    u16* wt_cav = wt_cak + 6 * 16384;
    u16* wt_cao = wt_cav + 6 * 16384;
    u16* wt1  = (u16*)(ws + 3211776);         // [6][512][128] us = 196608 f
    u16* wt2  = (u16*)(ws + 3408384);         // [6][128][512] us = 196608 f

    wconv8_kernel<<<dim3(384, 1, 8), dim3(256), 0, stream>>>(
        sa_wq, sa_wk, sa_wv, sa_wo, ca_wq, ca_wk, ca_wv, ca_wo,
        wt_saq, wt_sak, wt_sav, wt_sao, wt_caq, wt_cak, wt_cav, wt_cao);
    wconvg_kernel<<<dim3(1536), dim3(256), 0, stream>>>(ff_w1, wt1, 7, 9);
    wconvg_kernel<<<dim3(1536), dim3(256), 0, stream>>>(ff_w2, wt2, 9, 7);
    zvt_kernel<<<dim3(32), dim3(256), 0, stream>>>(Vt);

    lat_h_kernel<<<dim3(2), dim3(256), 0, stream>>>(latent, lp_w1, lp_b1, hlat);
    dec_kernel<<<dim3(900), dim3(256), 0, stream>>>(hlat, lp_w2, lp_b2, x, xb, encb);

    const dim3 thr(256);
    const dim3 gFm(NQT + 1, 16), gFc(NQT, 16), gFuse(113);

    // layer-0 self-attn QKV from xb
    mm_qkv_kernel<<<dim3(57, 1, 3), thr, 0, stream>>>(
        xb, xb, wt_saq, wt_sak, wt_sav, sa_bq, sa_bk, sa_bv, Qb, Kb, Vt);

    for (int i = 0; i < Ln; ++i) {
        const size_t wOff = (size_t)i * 16384;
        const size_t bOff = (size_t)i * 128;
        const size_t fOff = (size_t)i * 65536;
        const size_t f1b  = (size_t)i * 512;
        const size_t wNxt = (size_t)(i + 1) * 16384;
        const size_t bNxt = (size_t)(i + 1) * 128;

        flash_mfma<1><<<gFm, thr, 0, stream>>>(Qb, Kb, Vt, ob);

        fuse_oln_qkv_kernel<<<gFuse, thr, 0, stream>>>(
            ob, wt_sao + wOff, sa_bo + bOff, ln1g + bOff, ln1b + bOff, x, encb,
            wt_caq + wOff, wt_cak + wOff, wt_cav + wOff,
            ca_bq + bOff, ca_bk + bOff, ca_bv + bOff, Qb, Kb, Vt);

        flash_mfma<0><<<gFc, thr, 0, stream>>>(Qb, Kb, Vt, ob);

        if (i < Ln - 1) {
            fuse_ffn_kernel<1><<<gFuse, thr, 0, stream>>>(
                ob, wt_cao + wOff, ca_bo + bOff, ln2g + bOff, ln2b + bOff,
                wt1 + fOff, ff_b1 + f1b, wt2 + fOff, ff_b2 + bOff,
                ln3g + bOff, ln3b + bOff, x,
                wt_saq + wNxt, wt_sak + wNxt, wt_sav + wNxt,
                sa_bq + bNxt, sa_bk + bNxt, sa_bv + bNxt, Qb, Kb, Vt);
        } else {
            fuse_ffn_kernel<0><<<gFuse, thr, 0, stream>>>(
                ob, wt_cao + wOff, ca_bo + bOff, ln2g + bOff, ln2b + bOff,
                wt1 + fOff, ff_b1 + f1b, wt2 + fOff, ff_b2 + bOff,
                ln3g + bOff, ln3b + bOff, x,
                wt_saq, wt_sak, wt_sav, sa_bq, sa_bk, sa_bv, Qb, Kb, Vt);
        }
    }

    out_kernel<<<dim3(225), dim3(256), 0, stream>>>(x, out_w, out_b, (float*)d_out);
}